// Round 2
// baseline (2894.130 us; speedup 1.0000x reference)
//
#include <hip/hip_runtime.h>

#define NN 50000
#define NE 800000
#define KD 128   // inner dim (IN_C == HID_C == 128)

// ---------------- degree / norm kernels ----------------
__global__ __launch_bounds__(256) void deg_init(float* deg, int n) {
    int i = blockIdx.x * 256 + threadIdx.x;
    if (i < n) deg[i] = 1.0f;               // self-loop
}
__global__ __launch_bounds__(256) void deg_accum(const int* __restrict__ dst, float* deg, int e) {
    int i = blockIdx.x * 256 + threadIdx.x;
    if (i < e) atomicAdd(&deg[dst[i]], 1.0f);
}
__global__ __launch_bounds__(256) void deg_finalize(float* deg, int n) {
    int i = blockIdx.x * 256 + threadIdx.x;
    if (i < n) deg[i] = rsqrtf(deg[i]);     // in-place -> dinv
}

// ---------------- GEMM: out[n,c] = sum_k Xin'[n,k] * W[c,k] ----------------
// IN_TR: input transform  x' = relu(dinv[row]*x + bin[k])   (layers 2,3 input)
// EPI==0: write  hs = acc*dinv[row]  to BOTH outA and outB (outB = self-loop init)
// EPI==1: write  relu(acc + bout[c]) to outA only (final projection)
template<int CO, bool IN_TR, int EPI>
__global__ __launch_bounds__(256) void gemm_k(
    const float* __restrict__ Xin, const float* __restrict__ W,
    const float* __restrict__ dinv, const float* __restrict__ bin,
    const float* __restrict__ bout,
    float* __restrict__ outA, float* __restrict__ outB)
{
    constexpr int ROWS = 16;                 // 50000/16 = 3125 blocks exactly
    __shared__ float Ws[CO * KD];            // XOR-swizzled on 16B granules
    __shared__ float Xs[ROWS * KD];

    const int t = threadIdx.x;
    const int row0 = blockIdx.x * ROWS;

    // ---- stage W into LDS, granule-swizzled so compute reads are conflict-free
    constexpr int GR = CO * KD / 4;          // float4 granules
    for (int gi = t; gi < GR; gi += 256) {
        int c = gi >> 5;                     // KD/4 = 32 granules per row
        int g = gi & 31;
        float4 w = *(const float4*)(W + c * KD + g * 4);
        int gs = g ^ (c & 7);
        *(float4*)(Ws + c * KD + gs * 4) = w;
    }
    // ---- stage X rows (optionally fused epilogue-of-previous-layer)
    constexpr int XR = ROWS * KD / 4;        // 512 granules
    for (int gi = t; gi < XR; gi += 256) {
        int r = gi >> 5;
        int g = gi & 31;
        float4 v = *(const float4*)(Xin + (size_t)(row0 + r) * KD + g * 4);
        if (IN_TR) {
            float dv = dinv[row0 + r];
            float4 bb = *(const float4*)(bin + g * 4);
            v.x = fmaxf(0.f, fmaf(dv, v.x, bb.x));
            v.y = fmaxf(0.f, fmaf(dv, v.y, bb.y));
            v.z = fmaxf(0.f, fmaf(dv, v.z, bb.z));
            v.w = fmaxf(0.f, fmaf(dv, v.w, bb.w));
        }
        *(float4*)(Xs + r * KD + g * 4) = v;
    }
    __syncthreads();

    constexpr int G  = 256 / CO;             // row-groups
    constexpr int RT = ROWS / G;             // rows per thread
    const int c  = t % CO;
    const int ty = t / CO;
    const int rbase = ty * RT;

    float acc[RT];
#pragma unroll
    for (int r = 0; r < RT; ++r) acc[r] = 0.f;

    const int csw = (c & 7);
#pragma unroll 4
    for (int g = 0; g < 32; ++g) {
        float4 w = *(const float4*)(Ws + c * KD + (g ^ csw) * 4);
#pragma unroll
        for (int r = 0; r < RT; ++r) {
            float4 x = *(const float4*)(Xs + (rbase + r) * KD + g * 4); // wave-broadcast
            acc[r] = fmaf(x.x, w.x, acc[r]);
            acc[r] = fmaf(x.y, w.y, acc[r]);
            acc[r] = fmaf(x.z, w.z, acc[r]);
            acc[r] = fmaf(x.w, w.w, acc[r]);
        }
    }

#pragma unroll
    for (int r = 0; r < RT; ++r) {
        int row = row0 + rbase + r;
        float v = acc[r];
        if (EPI == 0) {
            float hv = v * dinv[row];
            outA[(size_t)row * CO + c] = hv;   // Hs (gather source)
            outB[(size_t)row * CO + c] = hv;   // acc init = self-loop term
        } else {
            outA[(size_t)row * CO + c] = fmaxf(0.f, v + bout[c]);
        }
    }
}

// ---------------- edge scatter: acc[dst,:] += Hs[src,:] ----------------
// one thread per (edge, 4-channel chunk): NE * 32 threads total
__global__ __launch_bounds__(256) void scatter_k(
    const float* __restrict__ Hs, float* __restrict__ acc,
    const int* __restrict__ src, const int* __restrict__ dst)
{
    int idx = blockIdx.x * 256 + threadIdx.x;   // NE*32 = 25.6M
    int e  = idx >> 5;
    int c4 = (idx & 31) * 4;
    int s = src[e], d = dst[e];
    float4 v = *(const float4*)(Hs + (size_t)s * KD + c4);
    float* p = acc + (size_t)d * KD + c4;
    atomicAdd(p + 0, v.x);
    atomicAdd(p + 1, v.y);
    atomicAdd(p + 2, v.z);
    atomicAdd(p + 3, v.w);
}

extern "C" void kernel_launch(void* const* d_in, const int* in_sizes, int n_in,
                              void* d_out, int out_size, void* d_ws, size_t ws_size,
                              hipStream_t stream) {
    const float* x    = (const float*)d_in[0];
    const int*   ei   = (const int*)d_in[1];     // [2,E] int32
    const float* W1   = (const float*)d_in[2];
    const float* b1   = (const float*)d_in[3];
    const float* W2   = (const float*)d_in[4];
    const float* b2   = (const float*)d_in[5];
    const float* Wp   = (const float*)d_in[6];
    const float* bp   = (const float*)d_in[7];
    float* out = (float*)d_out;

    const int* esrc = ei;
    const int* edst = ei + NE;

    float* A    = (float*)d_ws;                   // Hs buffer   [N,128]
    float* B    = A + (size_t)NN * KD;            // acc buffer  [N,128]
    float* dinv = B + (size_t)NN * KD;            // [N]

    // 1) degrees -> dinv
    deg_init    <<<(NN + 255) / 256, 256, 0, stream>>>(dinv, NN);
    deg_accum   <<<(NE + 255) / 256, 256, 0, stream>>>(edst, dinv, NE);
    deg_finalize<<<(NN + 255) / 256, 256, 0, stream>>>(dinv, NN);

    const int GB = NN / 16;               // 3125 gemm blocks
    const int SB = (NE * 32) / 256;       // 100000 scatter blocks (1 thread = 1 edge x 4ch)

    // 2) layer 1: Hs1 = (x@W1^T)*dinv  -> A, B(init)
    gemm_k<128, false, 0><<<GB, 256, 0, stream>>>(x, W1, dinv, nullptr, nullptr, A, B);
    // 3) scatter edges: B[dst] += A[src]
    scatter_k<<<SB, 256, 0, stream>>>(A, B, esrc, edst);
    // 4) layer 2: input = relu(dinv*B + b1); Hs2 -> A, B(init)  (row-wise in-place on B)
    gemm_k<128, true, 0><<<GB, 256, 0, stream>>>(B, W2, dinv, b1, nullptr, A, B);
    // 5) scatter edges again
    scatter_k<<<SB, 256, 0, stream>>>(A, B, esrc, edst);
    // 6) head: out = relu( relu(dinv*B + b2) @ Wp^T + bp )
    gemm_k<64, true, 1><<<GB, 256, 0, stream>>>(B, Wp, dinv, b2, bp, out, nullptr);
}

// Round 3
// 545.881 us; speedup vs baseline: 5.3018x; 5.3018x over previous
//
#include <hip/hip_runtime.h>

#define NN 50000
#define NE 800000
#define KD 128   // inner dim (IN_C == HID_C == 128)

// ---------------- CSR build ----------------
__global__ __launch_bounds__(256) void zero_int(int* p, int n) {
    int i = blockIdx.x * 256 + threadIdx.x;
    if (i < n) p[i] = 0;
}
__global__ __launch_bounds__(256) void count_k(const int* __restrict__ dst, int* degi, int e) {
    int i = blockIdx.x * 256 + threadIdx.x;
    if (i < e) atomicAdd(&degi[dst[i]], 1);
}
// single-block two-level exclusive scan over degi -> rowptr, cursor; also dinv
__global__ __launch_bounds__(1024) void scan_k(const int* __restrict__ degi,
    int* __restrict__ rowptr, int* __restrict__ cursor, float* __restrict__ dinv, int n)
{
    const int T = 1024;
    int t = threadIdx.x;
    int per = (n + T - 1) / T;             // 49
    int b = t * per, e = min(b + per, n);
    int s = 0;
    for (int i = b; i < e; ++i) s += degi[i];
    __shared__ int sh[T];
    sh[t] = s; __syncthreads();
    for (int off = 1; off < T; off <<= 1) {
        int v = (t >= off) ? sh[t - off] : 0;
        __syncthreads();
        sh[t] += v;
        __syncthreads();
    }
    int run = sh[t] - s;                   // exclusive base for this thread's range
    for (int i = b; i < e; ++i) {
        int dv = degi[i];
        rowptr[i] = run; cursor[i] = run;
        dinv[i] = rsqrtf(1.0f + (float)dv);
        run += dv;
    }
    if (t == T - 1) rowptr[n] = sh[T - 1];
}
__global__ __launch_bounds__(256) void fill_k(const int* __restrict__ src,
    const int* __restrict__ dst, int* cursor, int* __restrict__ col, int e)
{
    int i = blockIdx.x * 256 + threadIdx.x;
    if (i < e) {
        int d = dst[i];
        int p = atomicAdd(&cursor[d], 1);
        col[p] = src[i];
    }
}

// ---------------- GEMM: outA[n,c] = epi( sum_k tr(Xin[n,k]) * W[c,k] ) ----------------
// IN_TR: input transform x' = relu(x + bin[k])      (layers 2,3: bias+relu of prev agg)
// EPI==0: write  hs = acc*dinv[row]   (gather source)
// EPI==1: write  relu(acc + bout[c])  (final projection)
template<int CO, bool IN_TR, int EPI>
__global__ __launch_bounds__(256) void gemm_k(
    const float* __restrict__ Xin, const float* __restrict__ W,
    const float* __restrict__ dinv, const float* __restrict__ bin,
    const float* __restrict__ bout, float* __restrict__ outA)
{
    constexpr int ROWS = 16;                 // 50000/16 = 3125 blocks exactly
    __shared__ float Ws[CO * KD];            // XOR-swizzled on 16B granules
    __shared__ float Xs[ROWS * KD];

    const int t = threadIdx.x;
    const int row0 = blockIdx.x * ROWS;

    constexpr int GR = CO * KD / 4;          // float4 granules of W
    for (int gi = t; gi < GR; gi += 256) {
        int c = gi >> 5;                     // KD/4 = 32 granules per row
        int g = gi & 31;
        float4 w = *(const float4*)(W + c * KD + g * 4);
        int gs = g ^ (c & 7);
        *(float4*)(Ws + c * KD + gs * 4) = w;
    }
    constexpr int XR = ROWS * KD / 4;        // 512 granules of X
    for (int gi = t; gi < XR; gi += 256) {
        int r = gi >> 5;
        int g = gi & 31;
        float4 v = *(const float4*)(Xin + (size_t)(row0 + r) * KD + g * 4);
        if (IN_TR) {
            float4 bb = *(const float4*)(bin + g * 4);
            v.x = fmaxf(0.f, v.x + bb.x);
            v.y = fmaxf(0.f, v.y + bb.y);
            v.z = fmaxf(0.f, v.z + bb.z);
            v.w = fmaxf(0.f, v.w + bb.w);
        }
        *(float4*)(Xs + r * KD + g * 4) = v;
    }
    __syncthreads();

    constexpr int G  = 256 / CO;
    constexpr int RT = ROWS / G;
    const int c  = t % CO;
    const int ty = t / CO;
    const int rbase = ty * RT;

    float acc[RT];
#pragma unroll
    for (int r = 0; r < RT; ++r) acc[r] = 0.f;

    const int csw = (c & 7);
#pragma unroll 4
    for (int g = 0; g < 32; ++g) {
        float4 w = *(const float4*)(Ws + c * KD + (g ^ csw) * 4);
#pragma unroll
        for (int r = 0; r < RT; ++r) {
            float4 x = *(const float4*)(Xs + (rbase + r) * KD + g * 4); // wave-broadcast
            acc[r] = fmaf(x.x, w.x, acc[r]);
            acc[r] = fmaf(x.y, w.y, acc[r]);
            acc[r] = fmaf(x.z, w.z, acc[r]);
            acc[r] = fmaf(x.w, w.w, acc[r]);
        }
    }

#pragma unroll
    for (int r = 0; r < RT; ++r) {
        int row = row0 + rbase + r;
        float v = acc[r];
        if (EPI == 0) {
            outA[(size_t)row * CO + c] = v * dinv[row];
        } else {
            outA[(size_t)row * CO + c] = fmaxf(0.f, v + bout[c]);
        }
    }
}

// ---------------- CSR gather: B[d,:] = dinv[d]*(A[d,:] + sum_{s in adj(d)} A[s,:]) ----
// one wave per node; lane owns channels [2*lane, 2*lane+1]
__global__ __launch_bounds__(256) void gather_k(
    const float* __restrict__ Hs, float* __restrict__ outB,
    const int* __restrict__ rowptr, const int* __restrict__ col,
    const float* __restrict__ dinv)
{
    int wave = threadIdx.x >> 6;
    int lane = threadIdx.x & 63;
    int d = blockIdx.x * 4 + wave;
    if (d >= NN) return;
    int beg = rowptr[d], end = rowptr[d + 1];

    float2 acc = ((const float2*)(Hs + (size_t)d * KD))[lane];  // self-loop term
    for (int j = beg; j < end; ++j) {
        int s = col[j];                                          // wave-uniform
        float2 v = ((const float2*)(Hs + (size_t)s * KD))[lane];
        acc.x += v.x; acc.y += v.y;
    }
    float dv = dinv[d];
    float2 r; r.x = acc.x * dv; r.y = acc.y * dv;
    ((float2*)(outB + (size_t)d * KD))[lane] = r;
}

extern "C" void kernel_launch(void* const* d_in, const int* in_sizes, int n_in,
                              void* d_out, int out_size, void* d_ws, size_t ws_size,
                              hipStream_t stream) {
    const float* x    = (const float*)d_in[0];
    const int*   ei   = (const int*)d_in[1];     // [2,E] int32
    const float* W1   = (const float*)d_in[2];
    const float* b1   = (const float*)d_in[3];
    const float* W2   = (const float*)d_in[4];
    const float* b2   = (const float*)d_in[5];
    const float* Wp   = (const float*)d_in[6];
    const float* bp   = (const float*)d_in[7];
    float* out = (float*)d_out;

    const int* esrc = ei;
    const int* edst = ei + NE;

    float* A      = (float*)d_ws;                  // Hs buffer   [N,128] 25.6 MB
    float* B      = A + (size_t)NN * KD;           // agg buffer  [N,128] 25.6 MB
    float* dinv   = B + (size_t)NN * KD;           // [N]
    int*   degi   = (int*)(dinv + NN);             // [N]
    int*   rowptr = degi + NN;                     // [N+1]
    int*   cursor = rowptr + NN + 1;               // [N]
    int*   col    = cursor + NN;                   // [E] 3.2 MB

    // ---- CSR by dst (+ dinv) ----
    zero_int<<<(NN + 255) / 256, 256, 0, stream>>>(degi, NN);
    count_k <<<(NE + 255) / 256, 256, 0, stream>>>(edst, degi, NE);
    scan_k  <<<1, 1024, 0, stream>>>(degi, rowptr, cursor, dinv, NN);
    fill_k  <<<(NE + 255) / 256, 256, 0, stream>>>(esrc, edst, cursor, col, NE);

    const int GB = NN / 16;             // 3125 gemm blocks
    const int AB = (NN + 3) / 4;        // 12500 gather blocks (4 waves/block)

    // layer 1
    gemm_k<128, false, 0><<<GB, 256, 0, stream>>>(x, W1, dinv, nullptr, nullptr, A);
    gather_k<<<AB, 256, 0, stream>>>(A, B, rowptr, col, dinv);
    // layer 2
    gemm_k<128, true, 0><<<GB, 256, 0, stream>>>(B, W2, dinv, b1, nullptr, A);
    gather_k<<<AB, 256, 0, stream>>>(A, B, rowptr, col, dinv);
    // head
    gemm_k<64, true, 1><<<GB, 256, 0, stream>>>(B, Wp, dinv, b2, bp, out);
}

// Round 4
// 397.501 us; speedup vs baseline: 7.2808x; 1.3733x over previous
//
#include <hip/hip_runtime.h>

#define NN 50000
#define NE 800000
#define KD 128   // inner dim (IN_C == HID_C == 128)

// ---------------- CSR build ----------------
__global__ __launch_bounds__(256) void zero_int(int* p, int n) {
    int i = blockIdx.x * 256 + threadIdx.x;
    if (i < n) p[i] = 0;
}
__global__ __launch_bounds__(256) void count_k(const int* __restrict__ dst, int* degi, int e) {
    int i = blockIdx.x * 256 + threadIdx.x;
    if (i < e) atomicAdd(&degi[dst[i]], 1);
}
// hierarchical exclusive scan: reduce -> scan partials -> final
__global__ __launch_bounds__(256) void reduce_k(const int* __restrict__ degi, int* part, int n) {
    __shared__ int sh[256];
    int t = threadIdx.x;
    int i = blockIdx.x * 256 + t;
    sh[t] = (i < n) ? degi[i] : 0;
    __syncthreads();
    for (int off = 128; off > 0; off >>= 1) {
        if (t < off) sh[t] += sh[t + off];
        __syncthreads();
    }
    if (t == 0) part[blockIdx.x] = sh[0];
}
__global__ __launch_bounds__(256) void scanp_k(int* part, int* rowptr, int np, int n) {
    __shared__ int sh[256];
    int t = threadIdx.x;
    int v = (t < np) ? part[t] : 0;
    sh[t] = v; __syncthreads();
    for (int off = 1; off < 256; off <<= 1) {
        int u = (t >= off) ? sh[t - off] : 0;
        __syncthreads();
        sh[t] += u;
        __syncthreads();
    }
    if (t < np) part[t] = sh[t] - v;          // exclusive block offsets
    if (t == 255) rowptr[n] = sh[255];        // total (= NE)
}
__global__ __launch_bounds__(256) void scanf_k(const int* __restrict__ degi,
    const int* __restrict__ part, int* __restrict__ rowptr, int* __restrict__ cursor,
    float* __restrict__ dinv, int n)
{
    __shared__ int sh[256];
    int t = threadIdx.x;
    int i = blockIdx.x * 256 + t;
    int v = (i < n) ? degi[i] : 0;
    sh[t] = v; __syncthreads();
    for (int off = 1; off < 256; off <<= 1) {
        int u = (t >= off) ? sh[t - off] : 0;
        __syncthreads();
        sh[t] += u;
        __syncthreads();
    }
    if (i < n) {
        int excl = sh[t] - v + part[blockIdx.x];
        rowptr[i] = excl; cursor[i] = excl;
        dinv[i] = rsqrtf(1.0f + (float)v);
    }
}
__global__ __launch_bounds__(256) void fill_k(const int* __restrict__ src,
    const int* __restrict__ dst, int* cursor, int* __restrict__ col, int e)
{
    int i = blockIdx.x * 256 + threadIdx.x;
    if (i < e) {
        int d = dst[i];
        int p = atomicAdd(&cursor[d], 1);
        col[p] = src[i];
    }
}

// ---------------- GEMM: outA[n,c] = epi( sum_k tr(Xin[n,k]) * W[c,k] ) ----------------
template<int CO, bool IN_TR, int EPI>
__global__ __launch_bounds__(256) void gemm_k(
    const float* __restrict__ Xin, const float* __restrict__ W,
    const float* __restrict__ dinv, const float* __restrict__ bin,
    const float* __restrict__ bout, float* __restrict__ outA)
{
    constexpr int ROWS = 16;                 // 50000/16 = 3125 blocks exactly
    __shared__ float Ws[CO * KD];            // XOR-swizzled on 16B granules
    __shared__ float Xs[ROWS * KD];

    const int t = threadIdx.x;
    const int row0 = blockIdx.x * ROWS;

    constexpr int GR = CO * KD / 4;          // float4 granules of W
    for (int gi = t; gi < GR; gi += 256) {
        int c = gi >> 5;                     // KD/4 = 32 granules per row
        int g = gi & 31;
        float4 w = *(const float4*)(W + c * KD + g * 4);
        int gs = g ^ (c & 7);
        *(float4*)(Ws + c * KD + gs * 4) = w;
    }
    constexpr int XR = ROWS * KD / 4;        // 512 granules of X
    for (int gi = t; gi < XR; gi += 256) {
        int r = gi >> 5;
        int g = gi & 31;
        float4 v = *(const float4*)(Xin + (size_t)(row0 + r) * KD + g * 4);
        if (IN_TR) {
            float4 bb = *(const float4*)(bin + g * 4);
            v.x = fmaxf(0.f, v.x + bb.x);
            v.y = fmaxf(0.f, v.y + bb.y);
            v.z = fmaxf(0.f, v.z + bb.z);
            v.w = fmaxf(0.f, v.w + bb.w);
        }
        *(float4*)(Xs + r * KD + g * 4) = v;
    }
    __syncthreads();

    constexpr int G  = 256 / CO;
    constexpr int RT = ROWS / G;
    const int c  = t % CO;
    const int ty = t / CO;
    const int rbase = ty * RT;

    float acc[RT];
#pragma unroll
    for (int r = 0; r < RT; ++r) acc[r] = 0.f;

    const int csw = (c & 7);
#pragma unroll 4
    for (int g = 0; g < 32; ++g) {
        float4 w = *(const float4*)(Ws + c * KD + (g ^ csw) * 4);
#pragma unroll
        for (int r = 0; r < RT; ++r) {
            float4 x = *(const float4*)(Xs + (rbase + r) * KD + g * 4); // wave-broadcast
            acc[r] = fmaf(x.x, w.x, acc[r]);
            acc[r] = fmaf(x.y, w.y, acc[r]);
            acc[r] = fmaf(x.z, w.z, acc[r]);
            acc[r] = fmaf(x.w, w.w, acc[r]);
        }
    }

#pragma unroll
    for (int r = 0; r < RT; ++r) {
        int row = row0 + rbase + r;
        float v = acc[r];
        if (EPI == 0) {
            outA[(size_t)row * CO + c] = v * dinv[row];
        } else {
            outA[(size_t)row * CO + c] = fmaxf(0.f, v + bout[c]);
        }
    }
}

// ---------------- CSR gather: B[d,:] = dinv[d]*(A[d,:] + sum_{s in adj(d)} A[s,:]) ----
// one wave per node; lane owns channels [2*lane, 2*lane+1]; 2-deep unroll for MLP
__global__ __launch_bounds__(256) void gather_k(
    const float* __restrict__ Hs, float* __restrict__ outB,
    const int* __restrict__ rowptr, const int* __restrict__ col,
    const float* __restrict__ dinv)
{
    int wave = threadIdx.x >> 6;
    int lane = threadIdx.x & 63;
    int d = blockIdx.x * 4 + wave;
    if (d >= NN) return;
    int beg = rowptr[d], end = rowptr[d + 1];

    float2 a0 = ((const float2*)(Hs + (size_t)d * KD))[lane];  // self-loop term
    float2 a1 = make_float2(0.f, 0.f);
    int j = beg;
    for (; j + 1 < end; j += 2) {
        int s0 = col[j], s1 = col[j + 1];
        float2 v0 = ((const float2*)(Hs + (size_t)s0 * KD))[lane];
        float2 v1 = ((const float2*)(Hs + (size_t)s1 * KD))[lane];
        a0.x += v0.x; a0.y += v0.y;
        a1.x += v1.x; a1.y += v1.y;
    }
    if (j < end) {
        int s = col[j];
        float2 v = ((const float2*)(Hs + (size_t)s * KD))[lane];
        a0.x += v.x; a0.y += v.y;
    }
    float dv = dinv[d];
    float2 r; r.x = (a0.x + a1.x) * dv; r.y = (a0.y + a1.y) * dv;
    ((float2*)(outB + (size_t)d * KD))[lane] = r;
}

extern "C" void kernel_launch(void* const* d_in, const int* in_sizes, int n_in,
                              void* d_out, int out_size, void* d_ws, size_t ws_size,
                              hipStream_t stream) {
    const float* x    = (const float*)d_in[0];
    const int*   ei   = (const int*)d_in[1];     // [2,E] int32
    const float* W1   = (const float*)d_in[2];
    const float* b1   = (const float*)d_in[3];
    const float* W2   = (const float*)d_in[4];
    const float* b2   = (const float*)d_in[5];
    const float* Wp   = (const float*)d_in[6];
    const float* bp   = (const float*)d_in[7];
    float* out = (float*)d_out;

    const int* esrc = ei;
    const int* edst = ei + NE;

    float* A      = (float*)d_ws;                  // Hs buffer   [N,128] 25.6 MB
    float* B      = A + (size_t)NN * KD;           // agg buffer  [N,128] 25.6 MB
    float* dinv   = B + (size_t)NN * KD;           // [N]
    int*   degi   = (int*)(dinv + NN);             // [N]
    int*   rowptr = degi + NN;                     // [N+1]
    int*   cursor = rowptr + NN + 1;               // [N]
    int*   col    = cursor + NN;                   // [E] 3.2 MB
    int*   part   = col + NE;                      // [196]

    const int NB = (NN + 255) / 256;               // 196

    // ---- CSR by dst (+ dinv) ----
    zero_int<<<NB, 256, 0, stream>>>(degi, NN);
    count_k <<<(NE + 255) / 256, 256, 0, stream>>>(edst, degi, NE);
    reduce_k<<<NB, 256, 0, stream>>>(degi, part, NN);
    scanp_k <<<1, 256, 0, stream>>>(part, rowptr, NB, NN);
    scanf_k <<<NB, 256, 0, stream>>>(degi, part, rowptr, cursor, dinv, NN);
    fill_k  <<<(NE + 255) / 256, 256, 0, stream>>>(esrc, edst, cursor, col, NE);

    const int GB = NN / 16;             // 3125 gemm blocks
    const int AB = (NN + 3) / 4;        // 12500 gather blocks (4 waves/block)

    // layer 1
    gemm_k<128, false, 0><<<GB, 256, 0, stream>>>(x, W1, dinv, nullptr, nullptr, A);
    gather_k<<<AB, 256, 0, stream>>>(A, B, rowptr, col, dinv);
    // layer 2
    gemm_k<128, true, 0><<<GB, 256, 0, stream>>>(B, W2, dinv, b1, nullptr, A);
    gather_k<<<AB, 256, 0, stream>>>(A, B, rowptr, col, dinv);
    // head
    gemm_k<64, true, 1><<<GB, 256, 0, stream>>>(B, Wp, dinv, b2, bp, out);
}

// Round 5
// 307.506 us; speedup vs baseline: 9.4116x; 1.2927x over previous
//
#include <hip/hip_runtime.h>

#define NN 50000
#define NE 800000
#define KD 128   // inner dim (IN_C == HID_C == 128)

typedef __attribute__((ext_vector_type(8))) short short8;
typedef __attribute__((ext_vector_type(4))) float f32x4;

// ---------------- CSR build ----------------
__global__ __launch_bounds__(256) void zero_int(int* p, int n) {
    int i = blockIdx.x * 256 + threadIdx.x;
    if (i < n) p[i] = 0;
}
__global__ __launch_bounds__(256) void count_k(const int* __restrict__ dst, int* degi, int e) {
    int i = blockIdx.x * 256 + threadIdx.x;
    if (i < e) atomicAdd(&degi[dst[i]], 1);
}
__global__ __launch_bounds__(256) void reduce_k(const int* __restrict__ degi, int* part, int n) {
    __shared__ int sh[256];
    int t = threadIdx.x;
    int i = blockIdx.x * 256 + t;
    sh[t] = (i < n) ? degi[i] : 0;
    __syncthreads();
    for (int off = 128; off > 0; off >>= 1) {
        if (t < off) sh[t] += sh[t + off];
        __syncthreads();
    }
    if (t == 0) part[blockIdx.x] = sh[0];
}
__global__ __launch_bounds__(256) void scanp_k(int* part, int* rowptr, int np, int n) {
    __shared__ int sh[256];
    int t = threadIdx.x;
    int v = (t < np) ? part[t] : 0;
    sh[t] = v; __syncthreads();
    for (int off = 1; off < 256; off <<= 1) {
        int u = (t >= off) ? sh[t - off] : 0;
        __syncthreads();
        sh[t] += u;
        __syncthreads();
    }
    if (t < np) part[t] = sh[t] - v;
    if (t == 255) rowptr[n] = sh[255];
}
__global__ __launch_bounds__(256) void scanf_k(const int* __restrict__ degi,
    const int* __restrict__ part, int* __restrict__ rowptr, int* __restrict__ cursor,
    float* __restrict__ dinv, int n)
{
    __shared__ int sh[256];
    int t = threadIdx.x;
    int i = blockIdx.x * 256 + t;
    int v = (i < n) ? degi[i] : 0;
    sh[t] = v; __syncthreads();
    for (int off = 1; off < 256; off <<= 1) {
        int u = (t >= off) ? sh[t - off] : 0;
        __syncthreads();
        sh[t] += u;
        __syncthreads();
    }
    if (i < n) {
        int excl = sh[t] - v + part[blockIdx.x];
        rowptr[i] = excl; cursor[i] = excl;
        dinv[i] = rsqrtf(1.0f + (float)v);
    }
}
__global__ __launch_bounds__(256) void fill_k(const int* __restrict__ src,
    const int* __restrict__ dst, int* cursor, int* __restrict__ col, int e)
{
    int i = blockIdx.x * 256 + threadIdx.x;
    if (i < e) {
        int d = dst[i];
        int p = atomicAdd(&cursor[d], 1);
        col[p] = src[i];
    }
}

// ---------------- bf16 split helper ----------------
__device__ inline void splitbf(float x, short& h, short& l) {
    unsigned int u = __float_as_uint(x);
    unsigned int r = u + 0x8000u;                 // round-to-nearest on hi
    short hh = (short)(r >> 16);
    float hf = __uint_as_float(((unsigned int)(unsigned short)hh) << 16);
    float lo = x - hf;
    unsigned int u2 = __float_as_uint(lo) + 0x8000u;
    h = hh;
    l = (short)(u2 >> 16);
}

// ---------------- MFMA GEMM: outA[n,c] = epi( sum_k tr(Xin[n,k]) * W[c,k] ) --------
// fp32 emulated as bf16 split: x*w ~= xh*wh + xh*wl + xl*wh  (ll term dropped)
// 64 rows/block, 4 waves (16 rows each), mfma_f32_16x16x32_bf16.
template<int CO, bool IN_TR, int EPI>
__global__ __launch_bounds__(256) void mgemm_k(
    const float* __restrict__ Xin, const float* __restrict__ W,
    const float* __restrict__ dinv, const float* __restrict__ bin,
    const float* __restrict__ bout, float* __restrict__ outA)
{
    __shared__ short8 WhV[CO * 16];   // [c][granule], granule = 8 bf16 of k
    __shared__ short8 WlV[CO * 16];   // XOR-swizzled: slot = G ^ (c & 15)

    const int t = threadIdx.x;

    // ---- stage + split W (row-major [CO][128] fp32 -> bf16 hi/lo, swizzled)
    for (int i = t; i < CO * 16; i += 256) {
        int c = i >> 4, G = i & 15;
        const float* wp = W + c * KD + G * 8;
        float4 w0 = *(const float4*)wp;
        float4 w1 = *(const float4*)(wp + 4);
        float xs[8] = {w0.x, w0.y, w0.z, w0.w, w1.x, w1.y, w1.z, w1.w};
        short8 h, l;
#pragma unroll
        for (int j = 0; j < 8; ++j) { short hh, ll; splitbf(xs[j], hh, ll); h[j] = hh; l[j] = ll; }
        int Gs = G ^ (c & 15);
        WhV[c * 16 + Gs] = h;
        WlV[c * 16 + Gs] = l;
    }
    __syncthreads();

    const int wv = t >> 6, l = t & 63, q = l >> 4, lr = l & 15;
    const int row0 = blockIdx.x * 64 + wv * 16;
    constexpr int NCT = CO / 16;

    f32x4 acc[NCT];
#pragma unroll
    for (int ct = 0; ct < NCT; ++ct) acc[ct] = (f32x4){0.f, 0.f, 0.f, 0.f};

    int xrow = row0 + lr; if (xrow > NN - 1) xrow = NN - 1;   // clamp (stores guarded)
    const float* xbase = Xin + (size_t)xrow * KD + q * 8;

#pragma unroll
    for (int kk = 0; kk < 4; ++kk) {
        float4 x0 = *(const float4*)(xbase + kk * 32);
        float4 x1 = *(const float4*)(xbase + kk * 32 + 4);
        float xs[8] = {x0.x, x0.y, x0.z, x0.w, x1.x, x1.y, x1.z, x1.w};
        if (IN_TR) {
            const float* bb = bin + kk * 32 + q * 8;
            float4 b0 = *(const float4*)bb;
            float4 b1 = *(const float4*)(bb + 4);
            float bs[8] = {b0.x, b0.y, b0.z, b0.w, b1.x, b1.y, b1.z, b1.w};
#pragma unroll
            for (int j = 0; j < 8; ++j) xs[j] = fmaxf(0.f, xs[j] + bs[j]);
        }
        short8 ah, al;
#pragma unroll
        for (int j = 0; j < 8; ++j) { short hh, ll; splitbf(xs[j], hh, ll); ah[j] = hh; al[j] = ll; }

#pragma unroll
        for (int ct = 0; ct < NCT; ++ct) {
            int c = ct * 16 + lr;
            int Gs = (kk * 4 + q) ^ (c & 15);
            short8 bh = WhV[c * 16 + Gs];
            short8 bl = WlV[c * 16 + Gs];
            acc[ct] = __builtin_amdgcn_mfma_f32_16x16x32_bf16(ah, bh, acc[ct], 0, 0, 0);
            acc[ct] = __builtin_amdgcn_mfma_f32_16x16x32_bf16(ah, bl, acc[ct], 0, 0, 0);
            acc[ct] = __builtin_amdgcn_mfma_f32_16x16x32_bf16(al, bh, acc[ct], 0, 0, 0);
        }
    }

    // ---- epilogue: D[row=(q*4+r)][col=lane&15] per C/D mapping
    float dv[4]; int rok[4];
#pragma unroll
    for (int r = 0; r < 4; ++r) {
        int row = row0 + q * 4 + r;
        rok[r] = (row < NN);
        dv[r] = (EPI == 0 && rok[r]) ? dinv[row] : 0.f;
    }
#pragma unroll
    for (int ct = 0; ct < NCT; ++ct) {
        int c = ct * 16 + lr;
        float bc = (EPI == 1) ? bout[c] : 0.f;
#pragma unroll
        for (int r = 0; r < 4; ++r) {
            int row = row0 + q * 4 + r;
            if (rok[r]) {
                float v = acc[ct][r];
                if (EPI == 0) outA[(size_t)row * CO + c] = v * dv[r];
                else          outA[(size_t)row * CO + c] = fmaxf(0.f, v + bc);
            }
        }
    }
}

// ---------------- CSR gather: B[d,:] = dinv[d]*(A[d,:] + sum_{s in adj(d)} A[s,:]) ----
__global__ __launch_bounds__(256) void gather_k(
    const float* __restrict__ Hs, float* __restrict__ outB,
    const int* __restrict__ rowptr, const int* __restrict__ col,
    const float* __restrict__ dinv)
{
    int wave = threadIdx.x >> 6;
    int lane = threadIdx.x & 63;
    int d = blockIdx.x * 4 + wave;
    if (d >= NN) return;
    int beg = rowptr[d], end = rowptr[d + 1];

    float2 a0 = ((const float2*)(Hs + (size_t)d * KD))[lane];  // self-loop term
    float2 a1 = make_float2(0.f, 0.f);
    int j = beg;
    for (; j + 1 < end; j += 2) {
        int s0 = col[j], s1 = col[j + 1];
        float2 v0 = ((const float2*)(Hs + (size_t)s0 * KD))[lane];
        float2 v1 = ((const float2*)(Hs + (size_t)s1 * KD))[lane];
        a0.x += v0.x; a0.y += v0.y;
        a1.x += v1.x; a1.y += v1.y;
    }
    if (j < end) {
        int s = col[j];
        float2 v = ((const float2*)(Hs + (size_t)s * KD))[lane];
        a0.x += v.x; a0.y += v.y;
    }
    float dvv = dinv[d];
    float2 r; r.x = (a0.x + a1.x) * dvv; r.y = (a0.y + a1.y) * dvv;
    ((float2*)(outB + (size_t)d * KD))[lane] = r;
}

extern "C" void kernel_launch(void* const* d_in, const int* in_sizes, int n_in,
                              void* d_out, int out_size, void* d_ws, size_t ws_size,
                              hipStream_t stream) {
    const float* x    = (const float*)d_in[0];
    const int*   ei   = (const int*)d_in[1];     // [2,E] int32
    const float* W1   = (const float*)d_in[2];
    const float* b1   = (const float*)d_in[3];
    const float* W2   = (const float*)d_in[4];
    const float* b2   = (const float*)d_in[5];
    const float* Wp   = (const float*)d_in[6];
    const float* bp   = (const float*)d_in[7];
    float* out = (float*)d_out;

    const int* esrc = ei;
    const int* edst = ei + NE;

    float* A      = (float*)d_ws;                  // Hs buffer   [N,128] 25.6 MB
    float* B      = A + (size_t)NN * KD;           // agg buffer  [N,128] 25.6 MB
    float* dinv   = B + (size_t)NN * KD;           // [N]
    int*   degi   = (int*)(dinv + NN);             // [N]
    int*   rowptr = degi + NN;                     // [N+1]
    int*   cursor = rowptr + NN + 1;               // [N]
    int*   col    = cursor + NN;                   // [E] 3.2 MB
    int*   part   = col + NE;                      // [196]

    const int NB = (NN + 255) / 256;               // 196

    // ---- CSR by dst (+ dinv) ----
    zero_int<<<NB, 256, 0, stream>>>(degi, NN);
    count_k <<<(NE + 255) / 256, 256, 0, stream>>>(edst, degi, NE);
    reduce_k<<<NB, 256, 0, stream>>>(degi, part, NN);
    scanp_k <<<1, 256, 0, stream>>>(part, rowptr, NB, NN);
    scanf_k <<<NB, 256, 0, stream>>>(degi, part, rowptr, cursor, dinv, NN);
    fill_k  <<<(NE + 255) / 256, 256, 0, stream>>>(esrc, edst, cursor, col, NE);

    const int GB = (NN + 63) / 64;      // 782 mfma-gemm blocks
    const int AB = (NN + 3) / 4;        // 12500 gather blocks (4 waves/block)

    // layer 1
    mgemm_k<128, false, 0><<<GB, 256, 0, stream>>>(x, W1, dinv, nullptr, nullptr, A);
    gather_k<<<AB, 256, 0, stream>>>(A, B, rowptr, col, dinv);
    // layer 2
    mgemm_k<128, true, 0><<<GB, 256, 0, stream>>>(B, W2, dinv, b1, nullptr, A);
    gather_k<<<AB, 256, 0, stream>>>(A, B, rowptr, col, dinv);
    // head
    mgemm_k<64, true, 1><<<GB, 256, 0, stream>>>(B, Wp, dinv, b2, bp, out);
}

// Round 6
// 232.925 us; speedup vs baseline: 12.4251x; 1.3202x over previous
//
#include <hip/hip_runtime.h>

#define NN 50000
#define NE 800000
#define KD 128   // inner dim (IN_C == HID_C == 128)

typedef __attribute__((ext_vector_type(8))) short short8;
typedef __attribute__((ext_vector_type(4))) float f32x4;
typedef __attribute__((ext_vector_type(4))) unsigned short us4;

// ---------------- CSR build ----------------
__global__ __launch_bounds__(256) void zero_int(int* p, int n) {
    int i = blockIdx.x * 256 + threadIdx.x;
    if (i < n) p[i] = 0;
}
__global__ __launch_bounds__(256) void count_k(const int* __restrict__ dst, int* degi, int e) {
    int i = blockIdx.x * 256 + threadIdx.x;
    if (i < e) atomicAdd(&degi[dst[i]], 1);
}
__global__ __launch_bounds__(256) void reduce_k(const int* __restrict__ degi, int* part, int n) {
    __shared__ int sh[256];
    int t = threadIdx.x;
    int i = blockIdx.x * 256 + t;
    sh[t] = (i < n) ? degi[i] : 0;
    __syncthreads();
    for (int off = 128; off > 0; off >>= 1) {
        if (t < off) sh[t] += sh[t + off];
        __syncthreads();
    }
    if (t == 0) part[blockIdx.x] = sh[0];
}
__global__ __launch_bounds__(256) void scanp_k(int* part, int* rowptr, int np, int n) {
    __shared__ int sh[256];
    int t = threadIdx.x;
    int v = (t < np) ? part[t] : 0;
    sh[t] = v; __syncthreads();
    for (int off = 1; off < 256; off <<= 1) {
        int u = (t >= off) ? sh[t - off] : 0;
        __syncthreads();
        sh[t] += u;
        __syncthreads();
    }
    if (t < np) part[t] = sh[t] - v;
    if (t == 255) rowptr[n] = sh[255];
}
__global__ __launch_bounds__(256) void scanf_k(const int* __restrict__ degi,
    const int* __restrict__ part, int* __restrict__ rowptr, int* __restrict__ cursor,
    float* __restrict__ dinv, int n)
{
    __shared__ int sh[256];
    int t = threadIdx.x;
    int i = blockIdx.x * 256 + t;
    int v = (i < n) ? degi[i] : 0;
    sh[t] = v; __syncthreads();
    for (int off = 1; off < 256; off <<= 1) {
        int u = (t >= off) ? sh[t - off] : 0;
        __syncthreads();
        sh[t] += u;
        __syncthreads();
    }
    if (i < n) {
        int excl = sh[t] - v + part[blockIdx.x];
        rowptr[i] = excl; cursor[i] = excl;
        dinv[i] = rsqrtf(1.0f + (float)v);
    }
}
__global__ __launch_bounds__(256) void fill_k(const int* __restrict__ src,
    const int* __restrict__ dst, int* cursor, int* __restrict__ col, int e)
{
    int i = blockIdx.x * 256 + threadIdx.x;
    if (i < e) {
        int d = dst[i];
        int p = atomicAdd(&cursor[d], 1);
        col[p] = src[i];
    }
}

// ---------------- bf16 helpers ----------------
__device__ inline void splitbf(float x, short& h, short& l) {
    unsigned int u = __float_as_uint(x);
    unsigned int r = u + 0x8000u;                 // round-to-nearest on hi
    short hh = (short)(r >> 16);
    float hf = __uint_as_float(((unsigned int)(unsigned short)hh) << 16);
    float lo = x - hf;
    unsigned int u2 = __float_as_uint(lo) + 0x8000u;
    h = hh;
    l = (short)(u2 >> 16);
}
__device__ inline unsigned short f2bf(float x) {   // RTNE
    unsigned int u = __float_as_uint(x);
    unsigned int r = u + 0x7FFFu + ((u >> 16) & 1u);
    return (unsigned short)(r >> 16);
}
__device__ inline float bf2f(unsigned short b) {
    return __uint_as_float(((unsigned int)b) << 16);
}

// ---------------- MFMA GEMM: outA[n,c] = epi( sum_k tr(Xin[n,k]) * W[c,k] ) --------
// fp32 emulated as bf16 split: x*w ~= xh*wh + xh*wl + xl*wh  (ll term dropped)
// 64 rows/block, 4 waves (16 rows each), mfma_f32_16x16x32_bf16.
// EPI==0: write  (acc*dinv[row]) as bf16 to outA   (gather source, [N][CO] ushort)
// EPI==1: write  relu(acc + bout[c]) as fp32 to outA
template<int CO, bool IN_TR, int EPI>
__global__ __launch_bounds__(256) void mgemm_k(
    const float* __restrict__ Xin, const float* __restrict__ W,
    const float* __restrict__ dinv, const float* __restrict__ bin,
    const float* __restrict__ bout, void* __restrict__ outAv)
{
    __shared__ short8 WhV[CO * 16];   // [c][granule], granule = 8 bf16 of k
    __shared__ short8 WlV[CO * 16];   // XOR-swizzled: slot = G ^ (c & 15)

    const int t = threadIdx.x;

    for (int i = t; i < CO * 16; i += 256) {
        int c = i >> 4, G = i & 15;
        const float* wp = W + c * KD + G * 8;
        float4 w0 = *(const float4*)wp;
        float4 w1 = *(const float4*)(wp + 4);
        float xs[8] = {w0.x, w0.y, w0.z, w0.w, w1.x, w1.y, w1.z, w1.w};
        short8 h, l;
#pragma unroll
        for (int j = 0; j < 8; ++j) { short hh, ll; splitbf(xs[j], hh, ll); h[j] = hh; l[j] = ll; }
        int Gs = G ^ (c & 15);
        WhV[c * 16 + Gs] = h;
        WlV[c * 16 + Gs] = l;
    }
    __syncthreads();

    const int wv = t >> 6, l = t & 63, q = l >> 4, lr = l & 15;
    const int row0 = blockIdx.x * 64 + wv * 16;
    constexpr int NCT = CO / 16;

    f32x4 acc[NCT];
#pragma unroll
    for (int ct = 0; ct < NCT; ++ct) acc[ct] = (f32x4){0.f, 0.f, 0.f, 0.f};

    int xrow = row0 + lr; if (xrow > NN - 1) xrow = NN - 1;   // clamp (stores guarded)
    const float* xbase = Xin + (size_t)xrow * KD + q * 8;

#pragma unroll
    for (int kk = 0; kk < 4; ++kk) {
        float4 x0 = *(const float4*)(xbase + kk * 32);
        float4 x1 = *(const float4*)(xbase + kk * 32 + 4);
        float xs[8] = {x0.x, x0.y, x0.z, x0.w, x1.x, x1.y, x1.z, x1.w};
        if (IN_TR) {
            const float* bb = bin + kk * 32 + q * 8;
            float4 b0 = *(const float4*)bb;
            float4 b1 = *(const float4*)(bb + 4);
            float bs[8] = {b0.x, b0.y, b0.z, b0.w, b1.x, b1.y, b1.z, b1.w};
#pragma unroll
            for (int j = 0; j < 8; ++j) xs[j] = fmaxf(0.f, xs[j] + bs[j]);
        }
        short8 ah, al;
#pragma unroll
        for (int j = 0; j < 8; ++j) { short hh, ll; splitbf(xs[j], hh, ll); ah[j] = hh; al[j] = ll; }

#pragma unroll
        for (int ct = 0; ct < NCT; ++ct) {
            int c = ct * 16 + lr;
            int Gs = (kk * 4 + q) ^ (c & 15);
            short8 bh = WhV[c * 16 + Gs];
            short8 bl = WlV[c * 16 + Gs];
            acc[ct] = __builtin_amdgcn_mfma_f32_16x16x32_bf16(ah, bh, acc[ct], 0, 0, 0);
            acc[ct] = __builtin_amdgcn_mfma_f32_16x16x32_bf16(ah, bl, acc[ct], 0, 0, 0);
            acc[ct] = __builtin_amdgcn_mfma_f32_16x16x32_bf16(al, bh, acc[ct], 0, 0, 0);
        }
    }

    // ---- epilogue: D[row=(q*4+r)][col=lane&15] per C/D mapping
    float dv[4]; int rok[4];
#pragma unroll
    for (int r = 0; r < 4; ++r) {
        int row = row0 + q * 4 + r;
        rok[r] = (row < NN);
        dv[r] = (EPI == 0 && rok[r]) ? dinv[row] : 0.f;
    }
#pragma unroll
    for (int ct = 0; ct < NCT; ++ct) {
        int c = ct * 16 + lr;
        float bc = (EPI == 1) ? bout[c] : 0.f;
#pragma unroll
        for (int r = 0; r < 4; ++r) {
            int row = row0 + q * 4 + r;
            if (rok[r]) {
                float v = acc[ct][r];
                if (EPI == 0) {
                    ((unsigned short*)outAv)[(size_t)row * CO + c] = f2bf(v * dv[r]);
                } else {
                    ((float*)outAv)[(size_t)row * CO + c] = fmaxf(0.f, v + bc);
                }
            }
        }
    }
}

// ---------------- CSR gather: B[d,:] = dinv[d]*(A[d,:] + sum_{s in adj(d)} A[s,:]) ----
// A is bf16 [N][128] (256B/row). Half-wave layout: 32 lanes x 8B cover one row;
// even/odd neighbor parities run on the two halves -> 2 rows/instr, 4 in flight.
__global__ __launch_bounds__(256) void gather_k(
    const unsigned short* __restrict__ Hs, float* __restrict__ outB,
    const int* __restrict__ rowptr, const int* __restrict__ col,
    const float* __restrict__ dinv)
{
    int wave = threadIdx.x >> 6;
    int lane = threadIdx.x & 63;
    int h  = lane >> 5;          // neighbor parity handled by this half-wave
    int sl = lane & 31;          // channel chunk: channels [4*sl, 4*sl+3]
    int d = blockIdx.x * 4 + wave;
    if (d >= NN) return;
    int beg = rowptr[d], end = rowptr[d + 1];

    const unsigned short* hp = Hs + sl * 4;

    float4 a0 = make_float4(0.f, 0.f, 0.f, 0.f);
    float4 a1 = make_float4(0.f, 0.f, 0.f, 0.f);

    if (h == 0) {                                   // self-loop term on even half
        us4 v = *(const us4*)(hp + (size_t)d * KD);
        a0.x = bf2f(v[0]); a0.y = bf2f(v[1]); a0.z = bf2f(v[2]); a0.w = bf2f(v[3]);
    }

    int j = beg + h;
    for (; j + 2 < end; j += 4) {                   // 2-deep unroll, stride 2 per half
        int s0 = col[j], s1 = col[j + 2];
        us4 v0 = *(const us4*)(hp + (size_t)s0 * KD);
        us4 v1 = *(const us4*)(hp + (size_t)s1 * KD);
        a0.x += bf2f(v0[0]); a0.y += bf2f(v0[1]); a0.z += bf2f(v0[2]); a0.w += bf2f(v0[3]);
        a1.x += bf2f(v1[0]); a1.y += bf2f(v1[1]); a1.z += bf2f(v1[2]); a1.w += bf2f(v1[3]);
    }
    if (j < end) {
        int s = col[j];
        us4 v = *(const us4*)(hp + (size_t)s * KD);
        a0.x += bf2f(v[0]); a0.y += bf2f(v[1]); a0.z += bf2f(v[2]); a0.w += bf2f(v[3]);
    }

    float4 tt;
    tt.x = a0.x + a1.x; tt.y = a0.y + a1.y; tt.z = a0.z + a1.z; tt.w = a0.w + a1.w;
    tt.x += __shfl_xor(tt.x, 32);                   // combine parities across halves
    tt.y += __shfl_xor(tt.y, 32);
    tt.z += __shfl_xor(tt.z, 32);
    tt.w += __shfl_xor(tt.w, 32);

    if (h == 0) {
        float dvv = dinv[d];
        float4 r;
        r.x = tt.x * dvv; r.y = tt.y * dvv; r.z = tt.z * dvv; r.w = tt.w * dvv;
        *(float4*)(outB + (size_t)d * KD + sl * 4) = r;
    }
}

extern "C" void kernel_launch(void* const* d_in, const int* in_sizes, int n_in,
                              void* d_out, int out_size, void* d_ws, size_t ws_size,
                              hipStream_t stream) {
    const float* x    = (const float*)d_in[0];
    const int*   ei   = (const int*)d_in[1];     // [2,E] int32
    const float* W1   = (const float*)d_in[2];
    const float* b1   = (const float*)d_in[3];
    const float* W2   = (const float*)d_in[4];
    const float* b2   = (const float*)d_in[5];
    const float* Wp   = (const float*)d_in[6];
    const float* bp   = (const float*)d_in[7];
    float* out = (float*)d_out;

    const int* esrc = ei;
    const int* edst = ei + NE;

    unsigned short* A = (unsigned short*)d_ws;     // bf16 Hs   [N,128] 12.8 MB
    float* B      = (float*)(A + (size_t)NN * KD); // agg buffer [N,128] 25.6 MB fp32
    float* dinv   = B + (size_t)NN * KD;           // [N]
    int*   degi   = (int*)(dinv + NN);             // [N]
    int*   rowptr = degi + NN;                     // [N+1]
    int*   cursor = rowptr + NN + 1;               // [N]
    int*   col    = cursor + NN;                   // [E] 3.2 MB
    int*   part   = col + NE;                      // [196]

    const int NB = (NN + 255) / 256;               // 196

    // ---- CSR by dst (+ dinv) ----
    zero_int<<<NB, 256, 0, stream>>>(degi, NN);
    count_k <<<(NE + 255) / 256, 256, 0, stream>>>(edst, degi, NE);
    reduce_k<<<NB, 256, 0, stream>>>(degi, part, NN);
    scanp_k <<<1, 256, 0, stream>>>(part, rowptr, NB, NN);
    scanf_k <<<NB, 256, 0, stream>>>(degi, part, rowptr, cursor, dinv, NN);
    fill_k  <<<(NE + 255) / 256, 256, 0, stream>>>(esrc, edst, cursor, col, NE);

    const int GB = (NN + 63) / 64;      // 782 mfma-gemm blocks
    const int AB = (NN + 3) / 4;        // 12500 gather blocks (4 waves/block)

    // layer 1
    mgemm_k<128, false, 0><<<GB, 256, 0, stream>>>(x, W1, dinv, nullptr, nullptr, A);
    gather_k<<<AB, 256, 0, stream>>>(A, B, rowptr, col, dinv);
    // layer 2
    mgemm_k<128, true, 0><<<GB, 256, 0, stream>>>(B, W2, dinv, b1, nullptr, A);
    gather_k<<<AB, 256, 0, stream>>>(A, B, rowptr, col, dinv);
    // head
    mgemm_k<64, true, 1><<<GB, 256, 0, stream>>>(B, Wp, dinv, b2, bp, out);
}

// Round 7
// 194.083 us; speedup vs baseline: 14.9118x; 1.2001x over previous
//
#include <hip/hip_runtime.h>

#define NN 50000
#define NE 800000
#define KD 128    // inner dim (IN_C == HID_C == 128)
#define NBUK 196  // ceil(NN/256) buckets by dst>>8
#define CHUNK 2048

typedef __attribute__((ext_vector_type(8))) short short8;
typedef __attribute__((ext_vector_type(4))) float f32x4;
typedef __attribute__((ext_vector_type(4))) unsigned short us4;

// ---------------- CSR build: bucketed counting sort ----------------
// K1: per-block LDS histogram of dst>>8 -> global bucket counts
__global__ __launch_bounds__(256) void bcount_k(const int* __restrict__ dst, int* __restrict__ bcnt, int e) {
    __shared__ int h[NBUK];
    int t = threadIdx.x;
    int e0 = blockIdx.x * CHUNK, e1 = min(e0 + CHUNK, e);
    for (int i = t; i < NBUK; i += 256) h[i] = 0;
    __syncthreads();
    for (int i = e0 + t; i < e1; i += 256) atomicAdd(&h[dst[i] >> 8], 1);
    __syncthreads();
    for (int i = t; i < NBUK; i += 256) if (h[i]) atomicAdd(&bcnt[i], h[i]);
}
// K2: scan 196 bucket counts -> bbase, init bcur
__global__ __launch_bounds__(256) void bscan_k(const int* __restrict__ bcnt,
                                               int* __restrict__ bbase, int* __restrict__ bcur) {
    __shared__ int sh[256];
    int t = threadIdx.x;
    int v = (t < NBUK) ? bcnt[t] : 0;
    sh[t] = v; __syncthreads();
    for (int off = 1; off < 256; off <<= 1) {
        int u = (t >= off) ? sh[t - off] : 0;
        __syncthreads();
        sh[t] += u;
        __syncthreads();
    }
    if (t < NBUK) { int ex = sh[t] - v; bbase[t] = ex; bcur[t] = ex; }
}
// K3: scatter packed (src:u16, dst&255 in bits16-23) into bucket-contiguous pairs[]
// per-block: LDS hist -> ONE cursor claim per (block,bucket) -> ranked write runs
__global__ __launch_bounds__(256) void bscat_k(const int* __restrict__ src, const int* __restrict__ dst,
    int* __restrict__ bcur, unsigned int* __restrict__ pairs, int e)
{
    __shared__ int h[NBUK], base[NBUK], cur[NBUK];
    int t = threadIdx.x;
    int e0 = blockIdx.x * CHUNK, e1 = min(e0 + CHUNK, e);
    for (int i = t; i < NBUK; i += 256) { h[i] = 0; cur[i] = 0; }
    __syncthreads();
    for (int i = e0 + t; i < e1; i += 256) atomicAdd(&h[dst[i] >> 8], 1);
    __syncthreads();
    for (int i = t; i < NBUK; i += 256) base[i] = h[i] ? atomicAdd(&bcur[i], h[i]) : 0;
    __syncthreads();
    for (int i = e0 + t; i < e1; i += 256) {
        int d = dst[i];
        int b = d >> 8;
        int r = atomicAdd(&cur[b], 1);
        pairs[base[b] + r] = (unsigned)src[i] | ((unsigned)(d & 255) << 16);
    }
}
// K4: one block per bucket: hist 256 dsts -> scan -> rowptr/dinv; rank-scatter src into col
// (col region per bucket ~16KB, written by one block -> L2-local, ~1x amplification)
__global__ __launch_bounds__(256) void bbuild_k(const unsigned int* __restrict__ pairs,
    const int* __restrict__ bbase, const int* __restrict__ bcnt,
    int* __restrict__ rowptr, float* __restrict__ dinv, int* __restrict__ col)
{
    __shared__ int h[256], cur[256], exc[256], sh[256];
    int b = blockIdx.x, t = threadIdx.x;
    int base = bbase[b], nb = bcnt[b];
    int d0 = b << 8;
    int nd = NN - d0; if (nd > 256) nd = 256;
    h[t] = 0; cur[t] = 0;
    __syncthreads();
    for (int i = t; i < nb; i += 256) atomicAdd(&h[(pairs[base + i] >> 16) & 255], 1);
    __syncthreads();
    int v = h[t];
    sh[t] = v; __syncthreads();
    for (int off = 1; off < 256; off <<= 1) {
        int u = (t >= off) ? sh[t - off] : 0;
        __syncthreads();
        sh[t] += u;
        __syncthreads();
    }
    int ex = sh[t] - v;
    exc[t] = ex;
    if (t < nd) {
        rowptr[d0 + t] = base + ex;
        dinv[d0 + t] = rsqrtf(1.0f + (float)v);
        if (b == NBUK - 1 && t == nd - 1) rowptr[NN] = base + ex + v;  // = NE
    }
    __syncthreads();
    for (int i = t; i < nb; i += 256) {
        unsigned p = pairs[base + i];
        int dl = (p >> 16) & 255;
        int r = atomicAdd(&cur[dl], 1);
        col[base + exc[dl] + r] = (int)(p & 0xFFFFu);
    }
}

// ---------------- bf16 helpers ----------------
__device__ inline void splitbf(float x, short& h, short& l) {
    unsigned int u = __float_as_uint(x);
    unsigned int r = u + 0x8000u;                 // round-to-nearest on hi
    short hh = (short)(r >> 16);
    float hf = __uint_as_float(((unsigned int)(unsigned short)hh) << 16);
    float lo = x - hf;
    unsigned int u2 = __float_as_uint(lo) + 0x8000u;
    h = hh;
    l = (short)(u2 >> 16);
}
__device__ inline unsigned short f2bf(float x) {   // RTNE
    unsigned int u = __float_as_uint(x);
    unsigned int r = u + 0x7FFFu + ((u >> 16) & 1u);
    return (unsigned short)(r >> 16);
}
__device__ inline float bf2f(unsigned short b) {
    return __uint_as_float(((unsigned int)b) << 16);
}

// ---------------- MFMA GEMM: outA[n,c] = epi( sum_k tr(Xin[n,k]) * W[c,k] ) --------
// fp32 emulated as bf16 split: x*w ~= xh*wh + xh*wl + xl*wh  (ll term dropped)
// EPI==0: write (acc*dinv[row]) as bf16 (gather source); EPI==1: relu(acc+bout) fp32
template<int CO, bool IN_TR, int EPI>
__global__ __launch_bounds__(256) void mgemm_k(
    const float* __restrict__ Xin, const float* __restrict__ W,
    const float* __restrict__ dinv, const float* __restrict__ bin,
    const float* __restrict__ bout, void* __restrict__ outAv)
{
    __shared__ short8 WhV[CO * 16];   // [c][granule], granule = 8 bf16 of k
    __shared__ short8 WlV[CO * 16];   // XOR-swizzled: slot = G ^ (c & 15)

    const int t = threadIdx.x;

    for (int i = t; i < CO * 16; i += 256) {
        int c = i >> 4, G = i & 15;
        const float* wp = W + c * KD + G * 8;
        float4 w0 = *(const float4*)wp;
        float4 w1 = *(const float4*)(wp + 4);
        float xs[8] = {w0.x, w0.y, w0.z, w0.w, w1.x, w1.y, w1.z, w1.w};
        short8 h, l;
#pragma unroll
        for (int j = 0; j < 8; ++j) { short hh, ll; splitbf(xs[j], hh, ll); h[j] = hh; l[j] = ll; }
        int Gs = G ^ (c & 15);
        WhV[c * 16 + Gs] = h;
        WlV[c * 16 + Gs] = l;
    }
    __syncthreads();

    const int wv = t >> 6, l = t & 63, q = l >> 4, lr = l & 15;
    const int row0 = blockIdx.x * 64 + wv * 16;
    constexpr int NCT = CO / 16;

    f32x4 acc[NCT];
#pragma unroll
    for (int ct = 0; ct < NCT; ++ct) acc[ct] = (f32x4){0.f, 0.f, 0.f, 0.f};

    int xrow = row0 + lr; if (xrow > NN - 1) xrow = NN - 1;   // clamp (stores guarded)
    const float* xbase = Xin + (size_t)xrow * KD + q * 8;

#pragma unroll
    for (int kk = 0; kk < 4; ++kk) {
        float4 x0 = *(const float4*)(xbase + kk * 32);
        float4 x1 = *(const float4*)(xbase + kk * 32 + 4);
        float xs[8] = {x0.x, x0.y, x0.z, x0.w, x1.x, x1.y, x1.z, x1.w};
        if (IN_TR) {
            const float* bb = bin + kk * 32 + q * 8;
            float4 b0 = *(const float4*)bb;
            float4 b1 = *(const float4*)(bb + 4);
            float bs[8] = {b0.x, b0.y, b0.z, b0.w, b1.x, b1.y, b1.z, b1.w};
#pragma unroll
            for (int j = 0; j < 8; ++j) xs[j] = fmaxf(0.f, xs[j] + bs[j]);
        }
        short8 ah, al;
#pragma unroll
        for (int j = 0; j < 8; ++j) { short hh, ll; splitbf(xs[j], hh, ll); ah[j] = hh; al[j] = ll; }

#pragma unroll
        for (int ct = 0; ct < NCT; ++ct) {
            int c = ct * 16 + lr;
            int Gs = (kk * 4 + q) ^ (c & 15);
            short8 bh = WhV[c * 16 + Gs];
            short8 bl = WlV[c * 16 + Gs];
            acc[ct] = __builtin_amdgcn_mfma_f32_16x16x32_bf16(ah, bh, acc[ct], 0, 0, 0);
            acc[ct] = __builtin_amdgcn_mfma_f32_16x16x32_bf16(ah, bl, acc[ct], 0, 0, 0);
            acc[ct] = __builtin_amdgcn_mfma_f32_16x16x32_bf16(al, bh, acc[ct], 0, 0, 0);
        }
    }

    // ---- epilogue: D[row=(q*4+r)][col=lane&15] per C/D mapping
    float dv[4]; int rok[4];
#pragma unroll
    for (int r = 0; r < 4; ++r) {
        int row = row0 + q * 4 + r;
        rok[r] = (row < NN);
        dv[r] = (EPI == 0 && rok[r]) ? dinv[row] : 0.f;
    }
#pragma unroll
    for (int ct = 0; ct < NCT; ++ct) {
        int c = ct * 16 + lr;
        float bc = (EPI == 1) ? bout[c] : 0.f;
#pragma unroll
        for (int r = 0; r < 4; ++r) {
            int row = row0 + q * 4 + r;
            if (rok[r]) {
                float v = acc[ct][r];
                if (EPI == 0) {
                    ((unsigned short*)outAv)[(size_t)row * CO + c] = f2bf(v * dv[r]);
                } else {
                    ((float*)outAv)[(size_t)row * CO + c] = fmaxf(0.f, v + bc);
                }
            }
        }
    }
}

// ---------------- CSR gather: B[d,:] = dinv[d]*(A[d,:] + sum_{s in adj(d)} A[s,:]) ----
// A is bf16 [N][128] (256B/row). Half-wave layout: 32 lanes x 8B cover one row;
// even/odd neighbor parities run on the two halves -> 2 rows/instr, 4 in flight.
__global__ __launch_bounds__(256) void gather_k(
    const unsigned short* __restrict__ Hs, float* __restrict__ outB,
    const int* __restrict__ rowptr, const int* __restrict__ col,
    const float* __restrict__ dinv)
{
    int wave = threadIdx.x >> 6;
    int lane = threadIdx.x & 63;
    int h  = lane >> 5;          // neighbor parity handled by this half-wave
    int sl = lane & 31;          // channel chunk: channels [4*sl, 4*sl+3]
    int d = blockIdx.x * 4 + wave;
    if (d >= NN) return;
    int beg = rowptr[d], end = rowptr[d + 1];

    const unsigned short* hp = Hs + sl * 4;

    float4 a0 = make_float4(0.f, 0.f, 0.f, 0.f);
    float4 a1 = make_float4(0.f, 0.f, 0.f, 0.f);

    if (h == 0) {                                   // self-loop term on even half
        us4 v = *(const us4*)(hp + (size_t)d * KD);
        a0.x = bf2f(v[0]); a0.y = bf2f(v[1]); a0.z = bf2f(v[2]); a0.w = bf2f(v[3]);
    }

    int j = beg + h;
    for (; j + 2 < end; j += 4) {                   // 2-deep unroll, stride 2 per half
        int s0 = col[j], s1 = col[j + 2];
        us4 v0 = *(const us4*)(hp + (size_t)s0 * KD);
        us4 v1 = *(const us4*)(hp + (size_t)s1 * KD);
        a0.x += bf2f(v0[0]); a0.y += bf2f(v0[1]); a0.z += bf2f(v0[2]); a0.w += bf2f(v0[3]);
        a1.x += bf2f(v1[0]); a1.y += bf2f(v1[1]); a1.z += bf2f(v1[2]); a1.w += bf2f(v1[3]);
    }
    if (j < end) {
        int s = col[j];
        us4 v = *(const us4*)(hp + (size_t)s * KD);
        a0.x += bf2f(v[0]); a0.y += bf2f(v[1]); a0.z += bf2f(v[2]); a0.w += bf2f(v[3]);
    }

    float4 tt;
    tt.x = a0.x + a1.x; tt.y = a0.y + a1.y; tt.z = a0.z + a1.z; tt.w = a0.w + a1.w;
    tt.x += __shfl_xor(tt.x, 32);                   // combine parities across halves
    tt.y += __shfl_xor(tt.y, 32);
    tt.z += __shfl_xor(tt.z, 32);
    tt.w += __shfl_xor(tt.w, 32);

    if (h == 0) {
        float dvv = dinv[d];
        float4 r;
        r.x = tt.x * dvv; r.y = tt.y * dvv; r.z = tt.z * dvv; r.w = tt.w * dvv;
        *(float4*)(outB + (size_t)d * KD + sl * 4) = r;
    }
}

extern "C" void kernel_launch(void* const* d_in, const int* in_sizes, int n_in,
                              void* d_out, int out_size, void* d_ws, size_t ws_size,
                              hipStream_t stream) {
    const float* x    = (const float*)d_in[0];
    const int*   ei   = (const int*)d_in[1];     // [2,E] int32
    const float* W1   = (const float*)d_in[2];
    const float* b1   = (const float*)d_in[3];
    const float* W2   = (const float*)d_in[4];
    const float* b2   = (const float*)d_in[5];
    const float* Wp   = (const float*)d_in[6];
    const float* bp   = (const float*)d_in[7];
    float* out = (float*)d_out;

    const int* esrc = ei;
    const int* edst = ei + NE;

    unsigned short* A = (unsigned short*)d_ws;      // bf16 Hs   [N,128] 12.8 MB
    float* B      = (float*)(A + (size_t)NN * KD);  // agg buffer [N,128] 25.6 MB fp32
    float* dinv   = B + (size_t)NN * KD;            // [N]
    int*   rowptr = (int*)(dinv + NN);              // [N+1]
    int*   col    = rowptr + NN + 1;                // [E] 3.2 MB
    unsigned int* pairs = (unsigned int*)(col + NE);// [E] 3.2 MB
    int*   bcnt   = (int*)(pairs + NE);             // [NBUK]
    int*   bbase  = bcnt + NBUK;                    // [NBUK]
    int*   bcur   = bbase + NBUK;                   // [NBUK]

    const int NCH = (NE + CHUNK - 1) / CHUNK;       // 391

    // ---- CSR by dst (+ dinv) via bucketed counting sort ----
    hipMemsetAsync(bcnt, 0, NBUK * sizeof(int), stream);
    bcount_k<<<NCH, 256, 0, stream>>>(edst, bcnt, NE);
    bscan_k <<<1, 256, 0, stream>>>(bcnt, bbase, bcur);
    bscat_k <<<NCH, 256, 0, stream>>>(esrc, edst, bcur, pairs, NE);
    bbuild_k<<<NBUK, 256, 0, stream>>>(pairs, bbase, bcnt, rowptr, dinv, col);

    const int GB = (NN + 63) / 64;      // 782 mfma-gemm blocks
    const int AB = (NN + 3) / 4;        // 12500 gather blocks (4 waves/block)

    // layer 1
    mgemm_k<128, false, 0><<<GB, 256, 0, stream>>>(x, W1, dinv, nullptr, nullptr, A);
    gather_k<<<AB, 256, 0, stream>>>(A, B, rowptr, col, dinv);
    // layer 2
    mgemm_k<128, true, 0><<<GB, 256, 0, stream>>>(B, W2, dinv, b1, nullptr, A);
    gather_k<<<AB, 256, 0, stream>>>(A, B, rowptr, col, dinv);
    // head
    mgemm_k<64, true, 1><<<GB, 256, 0, stream>>>(B, Wp, dinv, b2, bp, out);
}

// Round 8
// 189.038 us; speedup vs baseline: 15.3097x; 1.0267x over previous
//
#include <hip/hip_runtime.h>

#define NN 50000
#define NE 800000
#define KD 128    // inner dim (IN_C == HID_C == 128)
#define NBUK 196  // ceil(NN/256) buckets by dst>>8
#define CHUNK 2048

typedef __attribute__((ext_vector_type(8))) short short8;
typedef __attribute__((ext_vector_type(4))) float f32x4;
typedef __attribute__((ext_vector_type(4))) unsigned short us4;

// ---------------- CSR build: bucketed counting sort ----------------
__global__ __launch_bounds__(256) void zero196_k(int* __restrict__ bcnt) {
    int t = threadIdx.x;
    if (t < NBUK) bcnt[t] = 0;
}
// K1: per-block LDS histogram of dst>>8 -> global bucket counts
__global__ __launch_bounds__(256) void bcount_k(const int* __restrict__ dst, int* __restrict__ bcnt, int e) {
    __shared__ int h[NBUK];
    int t = threadIdx.x;
    int e0 = blockIdx.x * CHUNK, e1 = min(e0 + CHUNK, e);
    for (int i = t; i < NBUK; i += 256) h[i] = 0;
    __syncthreads();
    for (int i = e0 + t; i < e1; i += 256) atomicAdd(&h[dst[i] >> 8], 1);
    __syncthreads();
    for (int i = t; i < NBUK; i += 256) if (h[i]) atomicAdd(&bcnt[i], h[i]);
}
// K2: scan 196 bucket counts -> bbase, init bcur
__global__ __launch_bounds__(256) void bscan_k(const int* __restrict__ bcnt,
                                               int* __restrict__ bbase, int* __restrict__ bcur) {
    __shared__ int sh[256];
    int t = threadIdx.x;
    int v = (t < NBUK) ? bcnt[t] : 0;
    sh[t] = v; __syncthreads();
    for (int off = 1; off < 256; off <<= 1) {
        int u = (t >= off) ? sh[t - off] : 0;
        __syncthreads();
        sh[t] += u;
        __syncthreads();
    }
    if (t < NBUK) { int ex = sh[t] - v; bbase[t] = ex; bcur[t] = ex; }
}
// K3: scatter packed (src:u16, dst&255 in bits16-23) into bucket-contiguous pairs[]
__global__ __launch_bounds__(256) void bscat_k(const int* __restrict__ src, const int* __restrict__ dst,
    int* __restrict__ bcur, unsigned int* __restrict__ pairs, int e)
{
    __shared__ int h[NBUK], base[NBUK], cur[NBUK];
    int t = threadIdx.x;
    int e0 = blockIdx.x * CHUNK, e1 = min(e0 + CHUNK, e);
    for (int i = t; i < NBUK; i += 256) { h[i] = 0; cur[i] = 0; }
    __syncthreads();
    for (int i = e0 + t; i < e1; i += 256) atomicAdd(&h[dst[i] >> 8], 1);
    __syncthreads();
    for (int i = t; i < NBUK; i += 256) base[i] = h[i] ? atomicAdd(&bcur[i], h[i]) : 0;
    __syncthreads();
    for (int i = e0 + t; i < e1; i += 256) {
        int d = dst[i];
        int b = d >> 8;
        int r = atomicAdd(&cur[b], 1);
        pairs[base[b] + r] = (unsigned)src[i] | ((unsigned)(d & 255) << 16);
    }
}
// K4: one block per bucket: hist 256 dsts -> scan -> rowptr/dinv; rank-scatter src into col
__global__ __launch_bounds__(256) void bbuild_k(const unsigned int* __restrict__ pairs,
    const int* __restrict__ bbase, const int* __restrict__ bcnt,
    int* __restrict__ rowptr, float* __restrict__ dinv, int* __restrict__ col)
{
    __shared__ int h[256], cur[256], exc[256], sh[256];
    int b = blockIdx.x, t = threadIdx.x;
    int base = bbase[b], nb = bcnt[b];
    int d0 = b << 8;
    int nd = NN - d0; if (nd > 256) nd = 256;
    h[t] = 0; cur[t] = 0;
    __syncthreads();
    for (int i = t; i < nb; i += 256) atomicAdd(&h[(pairs[base + i] >> 16) & 255], 1);
    __syncthreads();
    int v = h[t];
    sh[t] = v; __syncthreads();
    for (int off = 1; off < 256; off <<= 1) {
        int u = (t >= off) ? sh[t - off] : 0;
        __syncthreads();
        sh[t] += u;
        __syncthreads();
    }
    int ex = sh[t] - v;
    exc[t] = ex;
    if (t < nd) {
        rowptr[d0 + t] = base + ex;
        dinv[d0 + t] = rsqrtf(1.0f + (float)v);
        if (b == NBUK - 1 && t == nd - 1) rowptr[NN] = base + ex + v;  // = NE
    }
    __syncthreads();
    for (int i = t; i < nb; i += 256) {
        unsigned p = pairs[base + i];
        int dl = (p >> 16) & 255;
        int r = atomicAdd(&cur[dl], 1);
        col[base + exc[dl] + r] = (int)(p & 0xFFFFu);
    }
}

// ---------------- bf16 helpers ----------------
__device__ inline void splitbf(float x, short& h, short& l) {
    unsigned int u = __float_as_uint(x);
    unsigned int r = u + 0x8000u;                 // round-to-nearest on hi
    short hh = (short)(r >> 16);
    float hf = __uint_as_float(((unsigned int)(unsigned short)hh) << 16);
    float lo = x - hf;
    unsigned int u2 = __float_as_uint(lo) + 0x8000u;
    h = hh;
    l = (short)(u2 >> 16);
}
__device__ inline unsigned short f2bf(float x) {   // RTNE
    unsigned int u = __float_as_uint(x);
    unsigned int r = u + 0x7FFFu + ((u >> 16) & 1u);
    return (unsigned short)(r >> 16);
}
__device__ inline float bf2f(unsigned short b) {
    return __uint_as_float(((unsigned int)b) << 16);
}

// ---------------- MFMA GEMM: outA[n,c] = epi( sum_k tr(Xin[n,k]) * W[c,k] ) --------
// fp32 emulated as bf16 split: x*w ~= xh*wh + xh*wl + xl*wh  (ll term dropped)
// EPI==0: write (acc*dinv[row]) as bf16 (gather source); EPI==1: relu(acc+bout) fp32
template<int CO, bool IN_TR, int EPI>
__global__ __launch_bounds__(256) void mgemm_k(
    const float* __restrict__ Xin, const float* __restrict__ W,
    const float* __restrict__ dinv, const float* __restrict__ bin,
    const float* __restrict__ bout, void* __restrict__ outAv)
{
    __shared__ short8 WhV[CO * 16];   // [c][granule], granule = 8 bf16 of k
    __shared__ short8 WlV[CO * 16];   // XOR-swizzled: slot = G ^ (c & 15)

    const int t = threadIdx.x;

    for (int i = t; i < CO * 16; i += 256) {
        int c = i >> 4, G = i & 15;
        const float* wp = W + c * KD + G * 8;
        float4 w0 = *(const float4*)wp;
        float4 w1 = *(const float4*)(wp + 4);
        float xs[8] = {w0.x, w0.y, w0.z, w0.w, w1.x, w1.y, w1.z, w1.w};
        short8 h, l;
#pragma unroll
        for (int j = 0; j < 8; ++j) { short hh, ll; splitbf(xs[j], hh, ll); h[j] = hh; l[j] = ll; }
        int Gs = G ^ (c & 15);
        WhV[c * 16 + Gs] = h;
        WlV[c * 16 + Gs] = l;
    }
    __syncthreads();

    const int wv = t >> 6, l = t & 63, q = l >> 4, lr = l & 15;
    const int row0 = blockIdx.x * 64 + wv * 16;
    constexpr int NCT = CO / 16;

    f32x4 acc[NCT];
#pragma unroll
    for (int ct = 0; ct < NCT; ++ct) acc[ct] = (f32x4){0.f, 0.f, 0.f, 0.f};

    int xrow = row0 + lr; if (xrow > NN - 1) xrow = NN - 1;   // clamp (stores guarded)
    const float* xbase = Xin + (size_t)xrow * KD + q * 8;

#pragma unroll
    for (int kk = 0; kk < 4; ++kk) {
        float4 x0 = *(const float4*)(xbase + kk * 32);
        float4 x1 = *(const float4*)(xbase + kk * 32 + 4);
        float xs[8] = {x0.x, x0.y, x0.z, x0.w, x1.x, x1.y, x1.z, x1.w};
        if (IN_TR) {
            const float* bb = bin + kk * 32 + q * 8;
            float4 b0 = *(const float4*)bb;
            float4 b1 = *(const float4*)(bb + 4);
            float bs[8] = {b0.x, b0.y, b0.z, b0.w, b1.x, b1.y, b1.z, b1.w};
#pragma unroll
            for (int j = 0; j < 8; ++j) xs[j] = fmaxf(0.f, xs[j] + bs[j]);
        }
        short8 ah, al;
#pragma unroll
        for (int j = 0; j < 8; ++j) { short hh, ll; splitbf(xs[j], hh, ll); ah[j] = hh; al[j] = ll; }

#pragma unroll
        for (int ct = 0; ct < NCT; ++ct) {
            int c = ct * 16 + lr;
            int Gs = (kk * 4 + q) ^ (c & 15);
            short8 bh = WhV[c * 16 + Gs];
            short8 bl = WlV[c * 16 + Gs];
            acc[ct] = __builtin_amdgcn_mfma_f32_16x16x32_bf16(ah, bh, acc[ct], 0, 0, 0);
            acc[ct] = __builtin_amdgcn_mfma_f32_16x16x32_bf16(ah, bl, acc[ct], 0, 0, 0);
            acc[ct] = __builtin_amdgcn_mfma_f32_16x16x32_bf16(al, bh, acc[ct], 0, 0, 0);
        }
    }

    // ---- epilogue: D[row=(q*4+r)][col=lane&15] per C/D mapping
    float dv[4]; int rok[4];
#pragma unroll
    for (int r = 0; r < 4; ++r) {
        int row = row0 + q * 4 + r;
        rok[r] = (row < NN);
        dv[r] = (EPI == 0 && rok[r]) ? dinv[row] : 0.f;
    }
#pragma unroll
    for (int ct = 0; ct < NCT; ++ct) {
        int c = ct * 16 + lr;
        float bc = (EPI == 1) ? bout[c] : 0.f;
#pragma unroll
        for (int r = 0; r < 4; ++r) {
            int row = row0 + q * 4 + r;
            if (rok[r]) {
                float v = acc[ct][r];
                if (EPI == 0) {
                    ((unsigned short*)outAv)[(size_t)row * CO + c] = f2bf(v * dv[r]);
                } else {
                    ((float*)outAv)[(size_t)row * CO + c] = fmaxf(0.f, v + bc);
                }
            }
        }
    }
}

// ---------------- CSR gather: B[d,:] = dinv[d]*(A[d,:] + sum_{s in adj(d)} A[s,:]) ----
// A is bf16 [N][128] (256B/row). Half-wave layout: 32 lanes x 8B cover one row;
// even/odd neighbor parities run on the two halves -> 2 rows/instr, 4 in flight.
__global__ __launch_bounds__(256) void gather_k(
    const unsigned short* __restrict__ Hs, float* __restrict__ outB,
    const int* __restrict__ rowptr, const int* __restrict__ col,
    const float* __restrict__ dinv)
{
    int wave = threadIdx.x >> 6;
    int lane = threadIdx.x & 63;
    int h  = lane >> 5;          // neighbor parity handled by this half-wave
    int sl = lane & 31;          // channel chunk: channels [4*sl, 4*sl+3]
    int d = blockIdx.x * 4 + wave;
    if (d >= NN) return;
    int beg = rowptr[d], end = rowptr[d + 1];

    const unsigned short* hp = Hs + sl * 4;

    float4 a0 = make_float4(0.f, 0.f, 0.f, 0.f);
    float4 a1 = make_float4(0.f, 0.f, 0.f, 0.f);

    if (h == 0) {                                   // self-loop term on even half
        us4 v = *(const us4*)(hp + (size_t)d * KD);
        a0.x = bf2f(v[0]); a0.y = bf2f(v[1]); a0.z = bf2f(v[2]); a0.w = bf2f(v[3]);
    }

    int j = beg + h;
    for (; j + 2 < end; j += 4) {                   // 2-deep unroll, stride 2 per half
        int s0 = col[j], s1 = col[j + 2];
        us4 v0 = *(const us4*)(hp + (size_t)s0 * KD);
        us4 v1 = *(const us4*)(hp + (size_t)s1 * KD);
        a0.x += bf2f(v0[0]); a0.y += bf2f(v0[1]); a0.z += bf2f(v0[2]); a0.w += bf2f(v0[3]);
        a1.x += bf2f(v1[0]); a1.y += bf2f(v1[1]); a1.z += bf2f(v1[2]); a1.w += bf2f(v1[3]);
    }
    if (j < end) {
        int s = col[j];
        us4 v = *(const us4*)(hp + (size_t)s * KD);
        a0.x += bf2f(v[0]); a0.y += bf2f(v[1]); a0.z += bf2f(v[2]); a0.w += bf2f(v[3]);
    }

    float4 tt;
    tt.x = a0.x + a1.x; tt.y = a0.y + a1.y; tt.z = a0.z + a1.z; tt.w = a0.w + a1.w;
    tt.x += __shfl_xor(tt.x, 32);                   // combine parities across halves
    tt.y += __shfl_xor(tt.y, 32);
    tt.z += __shfl_xor(tt.z, 32);
    tt.w += __shfl_xor(tt.w, 32);

    if (h == 0) {
        float dvv = dinv[d];
        float4 r;
        r.x = tt.x * dvv; r.y = tt.y * dvv; r.z = tt.z * dvv; r.w = tt.w * dvv;
        *(float4*)(outB + (size_t)d * KD + sl * 4) = r;
    }
}

extern "C" void kernel_launch(void* const* d_in, const int* in_sizes, int n_in,
                              void* d_out, int out_size, void* d_ws, size_t ws_size,
                              hipStream_t stream) {
    const float* x    = (const float*)d_in[0];
    const int*   ei   = (const int*)d_in[1];     // [2,E] int32
    const float* W1   = (const float*)d_in[2];
    const float* b1   = (const float*)d_in[3];
    const float* W2   = (const float*)d_in[4];
    const float* b2   = (const float*)d_in[5];
    const float* Wp   = (const float*)d_in[6];
    const float* bp   = (const float*)d_in[7];
    float* out = (float*)d_out;

    const int* esrc = ei;
    const int* edst = ei + NE;

    unsigned short* A = (unsigned short*)d_ws;      // bf16 Hs   [N,128] 12.8 MB
    float* B      = (float*)(A + (size_t)NN * KD);  // agg buffer [N,128] 25.6 MB fp32
    float* dinv   = B + (size_t)NN * KD;            // [N]
    int*   rowptr = (int*)(dinv + NN);              // [N+1]
    int*   col    = rowptr + NN + 1;                // [E] 3.2 MB
    unsigned int* pairs = (unsigned int*)(col + NE);// [E] 3.2 MB
    int*   bcnt   = (int*)(pairs + NE);             // [NBUK]
    int*   bbase  = bcnt + NBUK;                    // [NBUK]
    int*   bcur   = bbase + NBUK;                   // [NBUK]

    const int NCH = (NE + CHUNK - 1) / CHUNK;       // 391

    // ---- CSR by dst (+ dinv) via bucketed counting sort ----
    zero196_k<<<1, 256, 0, stream>>>(bcnt);
    bcount_k<<<NCH, 256, 0, stream>>>(edst, bcnt, NE);
    bscan_k <<<1, 256, 0, stream>>>(bcnt, bbase, bcur);
    bscat_k <<<NCH, 256, 0, stream>>>(esrc, edst, bcur, pairs, NE);
    bbuild_k<<<NBUK, 256, 0, stream>>>(pairs, bbase, bcnt, rowptr, dinv, col);

    const int GB = (NN + 63) / 64;      // 782 mfma-gemm blocks
    const int AB = (NN + 3) / 4;        // 12500 gather blocks (4 waves/block)

    // layer 1
    mgemm_k<128, false, 0><<<GB, 256, 0, stream>>>(x, W1, dinv, nullptr, nullptr, A);
    gather_k<<<AB, 256, 0, stream>>>(A, B, rowptr, col, dinv);
    // layer 2
    mgemm_k<128, true, 0><<<GB, 256, 0, stream>>>(B, W2, dinv, b1, nullptr, A);
    gather_k<<<AB, 256, 0, stream>>>(A, B, rowptr, col, dinv);
    // head
    mgemm_k<64, true, 1><<<GB, 256, 0, stream>>>(B, Wp, dinv, b2, bp, out);
}

// Round 9
// 187.168 us; speedup vs baseline: 15.4627x; 1.0100x over previous
//
#include <hip/hip_runtime.h>

#define NN 50000
#define NE 800000
#define KD 128    // inner dim (IN_C == HID_C == 128)
#define NBUK 196  // ceil(NN/256) buckets by dst>>8
#define CHUNK 2048

typedef __attribute__((ext_vector_type(8))) short short8;
typedef __attribute__((ext_vector_type(4))) float f32x4;
typedef __attribute__((ext_vector_type(4))) unsigned short us4;

// ---------------- CSR build: bucketed counting sort ----------------
__global__ __launch_bounds__(256) void zero196_k(int* __restrict__ bcnt) {
    int t = threadIdx.x;
    if (t < NBUK) bcnt[t] = 0;
}
// K1: per-block LDS histogram of dst>>8 -> global bucket counts
__global__ __launch_bounds__(256) void bcount_k(const int* __restrict__ dst, int* __restrict__ bcnt, int e) {
    __shared__ int h[NBUK];
    int t = threadIdx.x;
    int e0 = blockIdx.x * CHUNK, e1 = min(e0 + CHUNK, e);
    for (int i = t; i < NBUK; i += 256) h[i] = 0;
    __syncthreads();
    for (int i = e0 + t; i < e1; i += 256) atomicAdd(&h[dst[i] >> 8], 1);
    __syncthreads();
    for (int i = t; i < NBUK; i += 256) if (h[i]) atomicAdd(&bcnt[i], h[i]);
}
// K2: scan 196 bucket counts -> bbase, init bcur
__global__ __launch_bounds__(256) void bscan_k(const int* __restrict__ bcnt,
                                               int* __restrict__ bbase, int* __restrict__ bcur) {
    __shared__ int sh[256];
    int t = threadIdx.x;
    int v = (t < NBUK) ? bcnt[t] : 0;
    sh[t] = v; __syncthreads();
    for (int off = 1; off < 256; off <<= 1) {
        int u = (t >= off) ? sh[t - off] : 0;
        __syncthreads();
        sh[t] += u;
        __syncthreads();
    }
    if (t < NBUK) { int ex = sh[t] - v; bbase[t] = ex; bcur[t] = ex; }
}
// K3: scatter packed (src:u16, dst&255 in bits16-23) into bucket-contiguous pairs[]
__global__ __launch_bounds__(256) void bscat_k(const int* __restrict__ src, const int* __restrict__ dst,
    int* __restrict__ bcur, unsigned int* __restrict__ pairs, int e)
{
    __shared__ int h[NBUK], base[NBUK], cur[NBUK];
    int t = threadIdx.x;
    int e0 = blockIdx.x * CHUNK, e1 = min(e0 + CHUNK, e);
    for (int i = t; i < NBUK; i += 256) { h[i] = 0; cur[i] = 0; }
    __syncthreads();
    for (int i = e0 + t; i < e1; i += 256) atomicAdd(&h[dst[i] >> 8], 1);
    __syncthreads();
    for (int i = t; i < NBUK; i += 256) base[i] = h[i] ? atomicAdd(&bcur[i], h[i]) : 0;
    __syncthreads();
    for (int i = e0 + t; i < e1; i += 256) {
        int d = dst[i];
        int b = d >> 8;
        int r = atomicAdd(&cur[b], 1);
        pairs[base[b] + r] = (unsigned)src[i] | ((unsigned)(d & 255) << 16);
    }
}
// K4: one block per bucket: hist 256 dsts -> scan -> rowptr/dinv; rank-scatter src into col
__global__ __launch_bounds__(256) void bbuild_k(const unsigned int* __restrict__ pairs,
    const int* __restrict__ bbase, const int* __restrict__ bcnt,
    int* __restrict__ rowptr, float* __restrict__ dinv, int* __restrict__ col)
{
    __shared__ int h[256], cur[256], exc[256], sh[256];
    int b = blockIdx.x, t = threadIdx.x;
    int base = bbase[b], nb = bcnt[b];
    int d0 = b << 8;
    int nd = NN - d0; if (nd > 256) nd = 256;
    h[t] = 0; cur[t] = 0;
    __syncthreads();
    for (int i = t; i < nb; i += 256) atomicAdd(&h[(pairs[base + i] >> 16) & 255], 1);
    __syncthreads();
    int v = h[t];
    sh[t] = v; __syncthreads();
    for (int off = 1; off < 256; off <<= 1) {
        int u = (t >= off) ? sh[t - off] : 0;
        __syncthreads();
        sh[t] += u;
        __syncthreads();
    }
    int ex = sh[t] - v;
    exc[t] = ex;
    if (t < nd) {
        rowptr[d0 + t] = base + ex;
        dinv[d0 + t] = rsqrtf(1.0f + (float)v);
        if (b == NBUK - 1 && t == nd - 1) rowptr[NN] = base + ex + v;  // = NE
    }
    __syncthreads();
    for (int i = t; i < nb; i += 256) {
        unsigned p = pairs[base + i];
        int dl = (p >> 16) & 255;
        int r = atomicAdd(&cur[dl], 1);
        col[base + exc[dl] + r] = (int)(p & 0xFFFFu);
    }
}

// ---------------- bf16 helpers ----------------
__device__ inline void splitbf(float x, short& h, short& l) {
    unsigned int u = __float_as_uint(x);
    unsigned int r = u + 0x8000u;                 // round-to-nearest on hi
    short hh = (short)(r >> 16);
    float hf = __uint_as_float(((unsigned int)(unsigned short)hh) << 16);
    float lo = x - hf;
    unsigned int u2 = __float_as_uint(lo) + 0x8000u;
    h = hh;
    l = (short)(u2 >> 16);
}
__device__ inline unsigned short f2bf(float x) {   // RTNE
    unsigned int u = __float_as_uint(x);
    unsigned int r = u + 0x7FFFu + ((u >> 16) & 1u);
    return (unsigned short)(r >> 16);
}
__device__ inline float bf2f(unsigned short b) {
    return __uint_as_float(((unsigned int)b) << 16);
}

// ---------------- MFMA GEMM: outA[n,c] = epi( sum_k tr(Xin[n,k]) * W[c,k] ) --------
// fp32 emulated as bf16 split: x*w ~= xh*wh + xh*wl + xl*wh  (ll term dropped)
// EPI==0: write (acc*dinv[row]) as bf16 (gather source); EPI==1: relu(acc+bout) fp32
template<int CO, bool IN_TR, int EPI>
__global__ __launch_bounds__(256) void mgemm_k(
    const float* __restrict__ Xin, const float* __restrict__ W,
    const float* __restrict__ dinv, const float* __restrict__ bin,
    const float* __restrict__ bout, void* __restrict__ outAv)
{
    __shared__ short8 WhV[CO * 16];   // [c][granule], granule = 8 bf16 of k
    __shared__ short8 WlV[CO * 16];   // XOR-swizzled: slot = G ^ (c & 15)

    const int t = threadIdx.x;

    for (int i = t; i < CO * 16; i += 256) {
        int c = i >> 4, G = i & 15;
        const float* wp = W + c * KD + G * 8;
        float4 w0 = *(const float4*)wp;
        float4 w1 = *(const float4*)(wp + 4);
        float xs[8] = {w0.x, w0.y, w0.z, w0.w, w1.x, w1.y, w1.z, w1.w};
        short8 h, l;
#pragma unroll
        for (int j = 0; j < 8; ++j) { short hh, ll; splitbf(xs[j], hh, ll); h[j] = hh; l[j] = ll; }
        int Gs = G ^ (c & 15);
        WhV[c * 16 + Gs] = h;
        WlV[c * 16 + Gs] = l;
    }
    __syncthreads();

    const int wv = t >> 6, l = t & 63, q = l >> 4, lr = l & 15;
    const int row0 = blockIdx.x * 64 + wv * 16;
    constexpr int NCT = CO / 16;

    f32x4 acc[NCT];
#pragma unroll
    for (int ct = 0; ct < NCT; ++ct) acc[ct] = (f32x4){0.f, 0.f, 0.f, 0.f};

    int xrow = row0 + lr; if (xrow > NN - 1) xrow = NN - 1;   // clamp (stores guarded)
    const float* xbase = Xin + (size_t)xrow * KD + q * 8;

#pragma unroll
    for (int kk = 0; kk < 4; ++kk) {
        float4 x0 = *(const float4*)(xbase + kk * 32);
        float4 x1 = *(const float4*)(xbase + kk * 32 + 4);
        float xs[8] = {x0.x, x0.y, x0.z, x0.w, x1.x, x1.y, x1.z, x1.w};
        if (IN_TR) {
            const float* bb = bin + kk * 32 + q * 8;
            float4 b0 = *(const float4*)bb;
            float4 b1 = *(const float4*)(bb + 4);
            float bs[8] = {b0.x, b0.y, b0.z, b0.w, b1.x, b1.y, b1.z, b1.w};
#pragma unroll
            for (int j = 0; j < 8; ++j) xs[j] = fmaxf(0.f, xs[j] + bs[j]);
        }
        short8 ah, al;
#pragma unroll
        for (int j = 0; j < 8; ++j) { short hh, ll; splitbf(xs[j], hh, ll); ah[j] = hh; al[j] = ll; }

#pragma unroll
        for (int ct = 0; ct < NCT; ++ct) {
            int c = ct * 16 + lr;
            int Gs = (kk * 4 + q) ^ (c & 15);
            short8 bh = WhV[c * 16 + Gs];
            short8 bl = WlV[c * 16 + Gs];
            acc[ct] = __builtin_amdgcn_mfma_f32_16x16x32_bf16(ah, bh, acc[ct], 0, 0, 0);
            acc[ct] = __builtin_amdgcn_mfma_f32_16x16x32_bf16(ah, bl, acc[ct], 0, 0, 0);
            acc[ct] = __builtin_amdgcn_mfma_f32_16x16x32_bf16(al, bh, acc[ct], 0, 0, 0);
        }
    }

    // ---- epilogue: D[row=(q*4+r)][col=lane&15] per C/D mapping
    float dv[4]; int rok[4];
#pragma unroll
    for (int r = 0; r < 4; ++r) {
        int row = row0 + q * 4 + r;
        rok[r] = (row < NN);
        dv[r] = (EPI == 0 && rok[r]) ? dinv[row] : 0.f;
    }
#pragma unroll
    for (int ct = 0; ct < NCT; ++ct) {
        int c = ct * 16 + lr;
        float bc = (EPI == 1) ? bout[c] : 0.f;
#pragma unroll
        for (int r = 0; r < 4; ++r) {
            int row = row0 + q * 4 + r;
            if (rok[r]) {
                float v = acc[ct][r];
                if (EPI == 0) {
                    ((unsigned short*)outAv)[(size_t)row * CO + c] = f2bf(v * dv[r]);
                } else {
                    ((float*)outAv)[(size_t)row * CO + c] = fmaxf(0.f, v + bc);
                }
            }
        }
    }
}

// ---------------- CSR gather: B[d,:] = dinv[d]*(A[d,:] + sum_{s in adj(d)} A[s,:]) ----
// A is bf16 [N][128] (256B/row). Half-wave layout: 32 lanes x 8B cover one row;
// even/odd neighbor parities on the two halves; 4-deep unroll -> 8 rows in flight/wave.
__global__ __launch_bounds__(256) void gather_k(
    const unsigned short* __restrict__ Hs, float* __restrict__ outB,
    const int* __restrict__ rowptr, const int* __restrict__ col,
    const float* __restrict__ dinv)
{
    int wave = threadIdx.x >> 6;
    int lane = threadIdx.x & 63;
    int h  = lane >> 5;          // neighbor parity handled by this half-wave
    int sl = lane & 31;          // channel chunk: channels [4*sl, 4*sl+3]
    int d = blockIdx.x * 4 + wave;
    if (d >= NN) return;
    int beg = rowptr[d], end = rowptr[d + 1];

    const unsigned short* hp = Hs + sl * 4;

    float4 a0 = make_float4(0.f, 0.f, 0.f, 0.f);
    float4 a1 = make_float4(0.f, 0.f, 0.f, 0.f);
    float4 a2 = make_float4(0.f, 0.f, 0.f, 0.f);
    float4 a3 = make_float4(0.f, 0.f, 0.f, 0.f);

    if (h == 0) {                                   // self-loop term on even half
        us4 v = *(const us4*)(hp + (size_t)d * KD);
        a0.x = bf2f(v[0]); a0.y = bf2f(v[1]); a0.z = bf2f(v[2]); a0.w = bf2f(v[3]);
    }

    int j = beg + h;
    for (; j + 6 < end; j += 8) {                   // 4-deep, stride 2 per half
        int s0 = col[j],     s1 = col[j + 2];
        int s2 = col[j + 4], s3 = col[j + 6];
        us4 v0 = *(const us4*)(hp + (size_t)s0 * KD);
        us4 v1 = *(const us4*)(hp + (size_t)s1 * KD);
        us4 v2 = *(const us4*)(hp + (size_t)s2 * KD);
        us4 v3 = *(const us4*)(hp + (size_t)s3 * KD);
        a0.x += bf2f(v0[0]); a0.y += bf2f(v0[1]); a0.z += bf2f(v0[2]); a0.w += bf2f(v0[3]);
        a1.x += bf2f(v1[0]); a1.y += bf2f(v1[1]); a1.z += bf2f(v1[2]); a1.w += bf2f(v1[3]);
        a2.x += bf2f(v2[0]); a2.y += bf2f(v2[1]); a2.z += bf2f(v2[2]); a2.w += bf2f(v2[3]);
        a3.x += bf2f(v3[0]); a3.y += bf2f(v3[1]); a3.z += bf2f(v3[2]); a3.w += bf2f(v3[3]);
    }
    for (; j < end; j += 2) {                       // remainder (up to 3 per half)
        int s = col[j];
        us4 v = *(const us4*)(hp + (size_t)s * KD);
        a0.x += bf2f(v[0]); a0.y += bf2f(v[1]); a0.z += bf2f(v[2]); a0.w += bf2f(v[3]);
    }

    float4 tt;
    tt.x = (a0.x + a1.x) + (a2.x + a3.x);
    tt.y = (a0.y + a1.y) + (a2.y + a3.y);
    tt.z = (a0.z + a1.z) + (a2.z + a3.z);
    tt.w = (a0.w + a1.w) + (a2.w + a3.w);
    tt.x += __shfl_xor(tt.x, 32);                   // combine parities across halves
    tt.y += __shfl_xor(tt.y, 32);
    tt.z += __shfl_xor(tt.z, 32);
    tt.w += __shfl_xor(tt.w, 32);

    if (h == 0) {
        float dvv = dinv[d];
        float4 r;
        r.x = tt.x * dvv; r.y = tt.y * dvv; r.z = tt.z * dvv; r.w = tt.w * dvv;
        *(float4*)(outB + (size_t)d * KD + sl * 4) = r;
    }
}

extern "C" void kernel_launch(void* const* d_in, const int* in_sizes, int n_in,
                              void* d_out, int out_size, void* d_ws, size_t ws_size,
                              hipStream_t stream) {
    const float* x    = (const float*)d_in[0];
    const int*   ei   = (const int*)d_in[1];     // [2,E] int32
    const float* W1   = (const float*)d_in[2];
    const float* b1   = (const float*)d_in[3];
    const float* W2   = (const float*)d_in[4];
    const float* b2   = (const float*)d_in[5];
    const float* Wp   = (const float*)d_in[6];
    const float* bp   = (const float*)d_in[7];
    float* out = (float*)d_out;

    const int* esrc = ei;
    const int* edst = ei + NE;

    unsigned short* A = (unsigned short*)d_ws;      // bf16 Hs   [N,128] 12.8 MB
    float* B      = (float*)(A + (size_t)NN * KD);  // agg buffer [N,128] 25.6 MB fp32
    float* dinv   = B + (size_t)NN * KD;            // [N]
    int*   rowptr = (int*)(dinv + NN);              // [N+1]
    int*   col    = rowptr + NN + 1;                // [E] 3.2 MB
    unsigned int* pairs = (unsigned int*)(col + NE);// [E] 3.2 MB
    int*   bcnt   = (int*)(pairs + NE);             // [NBUK]
    int*   bbase  = bcnt + NBUK;                    // [NBUK]
    int*   bcur   = bbase + NBUK;                   // [NBUK]

    const int NCH = (NE + CHUNK - 1) / CHUNK;       // 391

    // ---- CSR by dst (+ dinv) via bucketed counting sort ----
    zero196_k<<<1, 256, 0, stream>>>(bcnt);
    bcount_k<<<NCH, 256, 0, stream>>>(edst, bcnt, NE);
    bscan_k <<<1, 256, 0, stream>>>(bcnt, bbase, bcur);
    bscat_k <<<NCH, 256, 0, stream>>>(esrc, edst, bcur, pairs, NE);
    bbuild_k<<<NBUK, 256, 0, stream>>>(pairs, bbase, bcnt, rowptr, dinv, col);

    const int GB = (NN + 63) / 64;      // 782 mfma-gemm blocks
    const int AB = (NN + 3) / 4;        // 12500 gather blocks (4 waves/block)

    // layer 1
    mgemm_k<128, false, 0><<<GB, 256, 0, stream>>>(x, W1, dinv, nullptr, nullptr, A);
    gather_k<<<AB, 256, 0, stream>>>(A, B, rowptr, col, dinv);
    // layer 2
    mgemm_k<128, true, 0><<<GB, 256, 0, stream>>>(B, W2, dinv, b1, nullptr, A);
    gather_k<<<AB, 256, 0, stream>>>(A, B, rowptr, col, dinv);
    // head
    mgemm_k<64, true, 1><<<GB, 256, 0, stream>>>(B, Wp, dinv, b2, bp, out);
}

// Round 11
// 183.170 us; speedup vs baseline: 15.8002x; 1.0218x over previous
//
#include <hip/hip_runtime.h>

#define NN 50000
#define NE 800000
#define KD 128    // inner dim (IN_C == HID_C == 128)
#define NBUK 196  // ceil(NN/256) buckets by dst>>8
#define CHUNK 2048

typedef __attribute__((ext_vector_type(8))) short short8;
typedef __attribute__((ext_vector_type(4))) float f32x4;
typedef __attribute__((ext_vector_type(4))) unsigned short us4;

// ---------------- CSR build: bucketed counting sort ----------------
__global__ __launch_bounds__(256) void zero196_k(int* __restrict__ bcnt) {
    int t = threadIdx.x;
    if (t < NBUK) bcnt[t] = 0;
}
__global__ __launch_bounds__(256) void bcount_k(const int* __restrict__ dst, int* __restrict__ bcnt, int e) {
    __shared__ int h[NBUK];
    int t = threadIdx.x;
    int e0 = blockIdx.x * CHUNK, e1 = min(e0 + CHUNK, e);
    for (int i = t; i < NBUK; i += 256) h[i] = 0;
    __syncthreads();
    for (int i = e0 + t; i < e1; i += 256) atomicAdd(&h[dst[i] >> 8], 1);
    __syncthreads();
    for (int i = t; i < NBUK; i += 256) if (h[i]) atomicAdd(&bcnt[i], h[i]);
}
__global__ __launch_bounds__(256) void bscan_k(const int* __restrict__ bcnt,
                                               int* __restrict__ bbase, int* __restrict__ bcur) {
    __shared__ int sh[256];
    int t = threadIdx.x;
    int v = (t < NBUK) ? bcnt[t] : 0;
    sh[t] = v; __syncthreads();
    for (int off = 1; off < 256; off <<= 1) {
        int u = (t >= off) ? sh[t - off] : 0;
        __syncthreads();
        sh[t] += u;
        __syncthreads();
    }
    if (t < NBUK) { int ex = sh[t] - v; bbase[t] = ex; bcur[t] = ex; }
}
__global__ __launch_bounds__(256) void bscat_k(const int* __restrict__ src, const int* __restrict__ dst,
    int* __restrict__ bcur, unsigned int* __restrict__ pairs, int e)
{
    __shared__ int h[NBUK], base[NBUK], cur[NBUK];
    int t = threadIdx.x;
    int e0 = blockIdx.x * CHUNK, e1 = min(e0 + CHUNK, e);
    for (int i = t; i < NBUK; i += 256) { h[i] = 0; cur[i] = 0; }
    __syncthreads();
    for (int i = e0 + t; i < e1; i += 256) atomicAdd(&h[dst[i] >> 8], 1);
    __syncthreads();
    for (int i = t; i < NBUK; i += 256) base[i] = h[i] ? atomicAdd(&bcur[i], h[i]) : 0;
    __syncthreads();
    for (int i = e0 + t; i < e1; i += 256) {
        int d = dst[i];
        int b = d >> 8;
        int r = atomicAdd(&cur[b], 1);
        pairs[base[b] + r] = (unsigned)src[i] | ((unsigned)(d & 255) << 16);
    }
}
__global__ __launch_bounds__(256) void bbuild_k(const unsigned int* __restrict__ pairs,
    const int* __restrict__ bbase, const int* __restrict__ bcnt,
    int* __restrict__ rowptr, float* __restrict__ dinv, int* __restrict__ col)
{
    __shared__ int h[256], cur[256], exc[256], sh[256];
    int b = blockIdx.x, t = threadIdx.x;
    int base = bbase[b], nb = bcnt[b];
    int d0 = b << 8;
    int nd = NN - d0; if (nd > 256) nd = 256;
    h[t] = 0; cur[t] = 0;
    __syncthreads();
    for (int i = t; i < nb; i += 256) atomicAdd(&h[(pairs[base + i] >> 16) & 255], 1);
    __syncthreads();
    int v = h[t];
    sh[t] = v; __syncthreads();
    for (int off = 1; off < 256; off <<= 1) {
        int u = (t >= off) ? sh[t - off] : 0;
        __syncthreads();
        sh[t] += u;
        __syncthreads();
    }
    int ex = sh[t] - v;
    exc[t] = ex;
    if (t < nd) {
        rowptr[d0 + t] = base + ex;
        dinv[d0 + t] = rsqrtf(1.0f + (float)v);
        if (b == NBUK - 1 && t == nd - 1) rowptr[NN] = base + ex + v;  // = NE
    }
    __syncthreads();
    for (int i = t; i < nb; i += 256) {
        unsigned p = pairs[base + i];
        int dl = (p >> 16) & 255;
        int r = atomicAdd(&cur[dl], 1);
        col[base + exc[dl] + r] = (int)(p & 0xFFFFu);
    }
}

// ---------------- bf16 helpers ----------------
__device__ inline void splitbf(float x, short& h, short& l) {
    unsigned int u = __float_as_uint(x);
    unsigned int r = u + 0x8000u;                 // round-to-nearest on hi
    short hh = (short)(r >> 16);
    float hf = __uint_as_float(((unsigned int)(unsigned short)hh) << 16);
    float lo = x - hf;
    unsigned int u2 = __float_as_uint(lo) + 0x8000u;
    h = hh;
    l = (short)(u2 >> 16);
}
__device__ inline unsigned short f2bf(float x) {   // RTNE
    unsigned int u = __float_as_uint(x);
    unsigned int r = u + 0x7FFFu + ((u >> 16) & 1u);
    return (unsigned short)(r >> 16);
}
__device__ inline float bf2f(unsigned short b) {
    return __uint_as_float(((unsigned int)b) << 16);
}

// ---------------- MFMA GEMM: outA[n,c] = epi( sum_k Xin[n,k] * W[c,k] ) --------
// W split to bf16 hi/lo in LDS.
// XBF=false: X fp32, 3-term (xh*wh + xh*wl + xl*wh)  [layer 1]
// XBF=true:  X already bf16, 2-term (x*wh + x*wl)    [layer 2, head]
// EPI==0: write (acc*dinv[row]) bf16 (gather source); EPI==1: relu(acc+bout) fp32
template<int CO, bool XBF, int EPI>
__global__ __launch_bounds__(256) void mgemm_k(
    const void* __restrict__ Xin, const float* __restrict__ W,
    const float* __restrict__ dinv,
    const float* __restrict__ bout, void* __restrict__ outAv)
{
    __shared__ short8 WhV[CO * 16];   // [c][granule], granule = 8 bf16 of k
    __shared__ short8 WlV[CO * 16];   // XOR-swizzled: slot = G ^ (c & 15)

    const int t = threadIdx.x;

    for (int i = t; i < CO * 16; i += 256) {
        int c = i >> 4, G = i & 15;
        const float* wp = W + c * KD + G * 8;
        float4 w0 = *(const float4*)wp;
        float4 w1 = *(const float4*)(wp + 4);
        float xs[8] = {w0.x, w0.y, w0.z, w0.w, w1.x, w1.y, w1.z, w1.w};
        short8 h, l;
#pragma unroll
        for (int j = 0; j < 8; ++j) { short hh, ll; splitbf(xs[j], hh, ll); h[j] = hh; l[j] = ll; }
        int Gs = G ^ (c & 15);
        WhV[c * 16 + Gs] = h;
        WlV[c * 16 + Gs] = l;
    }
    __syncthreads();

    const int wv = t >> 6, l = t & 63, q = l >> 4, lr = l & 15;
    const int row0 = blockIdx.x * 64 + wv * 16;
    constexpr int NCT = CO / 16;

    f32x4 acc[NCT];
#pragma unroll
    for (int ct = 0; ct < NCT; ++ct) acc[ct] = (f32x4){0.f, 0.f, 0.f, 0.f};

    int xrow = row0 + lr; if (xrow > NN - 1) xrow = NN - 1;   // clamp (stores guarded)

#pragma unroll
    for (int kk = 0; kk < 4; ++kk) {
        short8 ah, al;
        if (XBF) {
            ah = *(const short8*)((const unsigned short*)Xin + (size_t)xrow * KD + q * 8 + kk * 32);
        } else {
            const float* xbase = (const float*)Xin + (size_t)xrow * KD + q * 8 + kk * 32;
            float4 x0 = *(const float4*)xbase;
            float4 x1 = *(const float4*)(xbase + 4);
            float xs[8] = {x0.x, x0.y, x0.z, x0.w, x1.x, x1.y, x1.z, x1.w};
#pragma unroll
            for (int j = 0; j < 8; ++j) { short hh, ll; splitbf(xs[j], hh, ll); ah[j] = hh; al[j] = ll; }
        }

#pragma unroll
        for (int ct = 0; ct < NCT; ++ct) {
            int c = ct * 16 + lr;
            int Gs = (kk * 4 + q) ^ (c & 15);
            short8 bh = WhV[c * 16 + Gs];
            short8 bl = WlV[c * 16 + Gs];
            acc[ct] = __builtin_amdgcn_mfma_f32_16x16x32_bf16(ah, bh, acc[ct], 0, 0, 0);
            acc[ct] = __builtin_amdgcn_mfma_f32_16x16x32_bf16(ah, bl, acc[ct], 0, 0, 0);
            if (!XBF)
                acc[ct] = __builtin_amdgcn_mfma_f32_16x16x32_bf16(al, bh, acc[ct], 0, 0, 0);
        }
    }

    // ---- epilogue: D[row=(q*4+r)][col=lane&15] per C/D mapping
    float dv[4]; int rok[4];
#pragma unroll
    for (int r = 0; r < 4; ++r) {
        int row = row0 + q * 4 + r;
        rok[r] = (row < NN);
        dv[r] = (EPI == 0 && rok[r]) ? dinv[row] : 0.f;
    }
#pragma unroll
    for (int ct = 0; ct < NCT; ++ct) {
        int c = ct * 16 + lr;
        float bc = (EPI == 1) ? bout[c] : 0.f;
#pragma unroll
        for (int r = 0; r < 4; ++r) {
            int row = row0 + q * 4 + r;
            if (rok[r]) {
                float v = acc[ct][r];
                if (EPI == 0) {
                    ((unsigned short*)outAv)[(size_t)row * CO + c] = f2bf(v * dv[r]);
                } else {
                    ((float*)outAv)[(size_t)row * CO + c] = fmaxf(0.f, v + bc);
                }
            }
        }
    }
}

// ---------------- CSR gather + next-layer input transform -----------------
// outX[d,:] = relu( dinv[d]*(A[d,:] + sum_{s in adj(d)} A[s,:]) + bias ) as bf16
// A bf16 [N][128]. R9-proven loop: direct col[j] loads, parity halves, 4-deep unroll.
__global__ __launch_bounds__(256) void gather_k(
    const unsigned short* __restrict__ Hs, unsigned short* __restrict__ outX,
    const int* __restrict__ rowptr, const int* __restrict__ col,
    const float* __restrict__ dinv, const float* __restrict__ bias)
{
    int wave = threadIdx.x >> 6;
    int lane = threadIdx.x & 63;
    int h  = lane >> 5;          // neighbor parity handled by this half-wave
    int sl = lane & 31;          // channel chunk: channels [4*sl, 4*sl+3]
    int d = blockIdx.x * 4 + wave;
    if (d >= NN) return;
    int beg = rowptr[d], end = rowptr[d + 1];

    const unsigned short* hp = Hs + sl * 4;
    float4 bb = *(const float4*)(bias + sl * 4);

    float4 a0 = make_float4(0.f, 0.f, 0.f, 0.f);
    float4 a1 = make_float4(0.f, 0.f, 0.f, 0.f);
    float4 a2 = make_float4(0.f, 0.f, 0.f, 0.f);
    float4 a3 = make_float4(0.f, 0.f, 0.f, 0.f);

    if (h == 0) {                                   // self-loop term on even half
        us4 v = *(const us4*)(hp + (size_t)d * KD);
        a0.x = bf2f(v[0]); a0.y = bf2f(v[1]); a0.z = bf2f(v[2]); a0.w = bf2f(v[3]);
    }

    int j = beg + h;
    for (; j + 6 < end; j += 8) {                   // 4-deep, stride 2 per half
        int s0 = col[j],     s1 = col[j + 2];
        int s2 = col[j + 4], s3 = col[j + 6];
        us4 v0 = *(const us4*)(hp + (size_t)s0 * KD);
        us4 v1 = *(const us4*)(hp + (size_t)s1 * KD);
        us4 v2 = *(const us4*)(hp + (size_t)s2 * KD);
        us4 v3 = *(const us4*)(hp + (size_t)s3 * KD);
        a0.x += bf2f(v0[0]); a0.y += bf2f(v0[1]); a0.z += bf2f(v0[2]); a0.w += bf2f(v0[3]);
        a1.x += bf2f(v1[0]); a1.y += bf2f(v1[1]); a1.z += bf2f(v1[2]); a1.w += bf2f(v1[3]);
        a2.x += bf2f(v2[0]); a2.y += bf2f(v2[1]); a2.z += bf2f(v2[2]); a2.w += bf2f(v2[3]);
        a3.x += bf2f(v3[0]); a3.y += bf2f(v3[1]); a3.z += bf2f(v3[2]); a3.w += bf2f(v3[3]);
    }
    for (; j < end; j += 2) {                       // remainder (same parity)
        int s = col[j];
        us4 v = *(const us4*)(hp + (size_t)s * KD);
        a0.x += bf2f(v[0]); a0.y += bf2f(v[1]); a0.z += bf2f(v[2]); a0.w += bf2f(v[3]);
    }

    float4 tt;
    tt.x = (a0.x + a1.x) + (a2.x + a3.x);
    tt.y = (a0.y + a1.y) + (a2.y + a3.y);
    tt.z = (a0.z + a1.z) + (a2.z + a3.z);
    tt.w = (a0.w + a1.w) + (a2.w + a3.w);
    tt.x += __shfl_xor(tt.x, 32);                   // combine parities across halves
    tt.y += __shfl_xor(tt.y, 32);
    tt.z += __shfl_xor(tt.z, 32);
    tt.w += __shfl_xor(tt.w, 32);

    if (h == 0) {
        float dvv = dinv[d];
        us4 r;
        r[0] = f2bf(fmaxf(0.f, tt.x * dvv + bb.x));
        r[1] = f2bf(fmaxf(0.f, tt.y * dvv + bb.y));
        r[2] = f2bf(fmaxf(0.f, tt.z * dvv + bb.z));
        r[3] = f2bf(fmaxf(0.f, tt.w * dvv + bb.w));
        *(us4*)(outX + (size_t)d * KD + sl * 4) = r;
    }
}

extern "C" void kernel_launch(void* const* d_in, const int* in_sizes, int n_in,
                              void* d_out, int out_size, void* d_ws, size_t ws_size,
                              hipStream_t stream) {
    const float* x    = (const float*)d_in[0];
    const int*   ei   = (const int*)d_in[1];     // [2,E] int32
    const float* W1   = (const float*)d_in[2];
    const float* b1   = (const float*)d_in[3];
    const float* W2   = (const float*)d_in[4];
    const float* b2   = (const float*)d_in[5];
    const float* Wp   = (const float*)d_in[6];
    const float* bp   = (const float*)d_in[7];
    float* out = (float*)d_out;

    const int* esrc = ei;
    const int* edst = ei + NE;

    unsigned short* A  = (unsigned short*)d_ws;       // bf16 Hs       [N,128] 12.8 MB
    unsigned short* X2 = A + (size_t)NN * KD;         // bf16 next-X   [N,128] 12.8 MB
    float* dinv   = (float*)(X2 + (size_t)NN * KD);   // [N]
    int*   rowptr = (int*)(dinv + NN);                // [N+1]
    int*   col    = rowptr + NN + 1;                  // [E] 3.2 MB
    unsigned int* pairs = (unsigned int*)(col + NE);  // [E] 3.2 MB
    int*   bcnt   = (int*)(pairs + NE);               // [NBUK]
    int*   bbase  = bcnt + NBUK;                      // [NBUK]
    int*   bcur   = bbase + NBUK;                     // [NBUK]

    const int NCH = (NE + CHUNK - 1) / CHUNK;         // 391

    // ---- CSR by dst (+ dinv) via bucketed counting sort ----
    zero196_k<<<1, 256, 0, stream>>>(bcnt);
    bcount_k<<<NCH, 256, 0, stream>>>(edst, bcnt, NE);
    bscan_k <<<1, 256, 0, stream>>>(bcnt, bbase, bcur);
    bscat_k <<<NCH, 256, 0, stream>>>(esrc, edst, bcur, pairs, NE);
    bbuild_k<<<NBUK, 256, 0, stream>>>(pairs, bbase, bcnt, rowptr, dinv, col);

    const int GB = (NN + 63) / 64;      // 782 mfma-gemm blocks
    const int AB = (NN + 3) / 4;        // 12500 gather blocks (4 waves/block)

    // layer 1: Hs1 = (x@W1^T)*dinv -> A (bf16)
    mgemm_k<128, false, 0><<<GB, 256, 0, stream>>>(x, W1, dinv, nullptr, A);
    // gather + transform: X2 = relu(dinv*(A+sum) + b1)  (bf16)
    gather_k<<<AB, 256, 0, stream>>>(A, X2, rowptr, col, dinv, b1);
    // layer 2: Hs2 = (X2@W2^T)*dinv -> A (bf16), 2-term MFMA
    mgemm_k<128, true, 0><<<GB, 256, 0, stream>>>(X2, W2, dinv, nullptr, A);
    // gather + transform: X2 = relu(dinv*(A+sum) + b2)  (bf16)
    gather_k<<<AB, 256, 0, stream>>>(A, X2, rowptr, col, dinv, b2);
    // head: out = relu(X2@Wp^T + bp)  fp32
    mgemm_k<64, true, 1><<<GB, 256, 0, stream>>>(X2, Wp, dinv, bp, out);
}

// Round 12
// 166.009 us; speedup vs baseline: 17.4336x; 1.1034x over previous
//
#include <hip/hip_runtime.h>

#define NN 50000
#define NE 800000
#define KD 128    // inner dim (IN_C == HID_C == 128)
#define NBUK 196  // ceil(NN/256) buckets by dst>>8
#define CHUNK 2048
#define SLACK 8192  // fixed bucket region size (mean 4082, +64 sigma safe)

typedef __attribute__((ext_vector_type(8))) short short8;
typedef __attribute__((ext_vector_type(4))) float f32x4;
typedef __attribute__((ext_vector_type(4))) unsigned short us4;

// ---------------- CSR build: direct-bucket counting sort (no count/scan passes) ----
__global__ __launch_bounds__(256) void zero196_k(int* __restrict__ bcur) {
    int t = threadIdx.x;
    if (t < NBUK) bcur[t] = 0;
}
// K1: per-chunk LDS histogram -> claim per-bucket runs off global cursors ->
//     write packed (src:u16, dst&255:bits16-23) into fixed-stride bucket regions
__global__ __launch_bounds__(256) void bscat_k(const int* __restrict__ src, const int* __restrict__ dst,
    int* __restrict__ bcur, unsigned int* __restrict__ pairs, int e)
{
    __shared__ int h[NBUK], base[NBUK], cur[NBUK];
    int t = threadIdx.x;
    int e0 = blockIdx.x * CHUNK, e1 = min(e0 + CHUNK, e);
    for (int i = t; i < NBUK; i += 256) { h[i] = 0; cur[i] = 0; }
    __syncthreads();
    for (int i = e0 + t; i < e1; i += 256) atomicAdd(&h[dst[i] >> 8], 1);
    __syncthreads();
    for (int i = t; i < NBUK; i += 256) base[i] = h[i] ? atomicAdd(&bcur[i], h[i]) : 0;
    __syncthreads();
    for (int i = e0 + t; i < e1; i += 256) {
        int d = dst[i];
        int b = d >> 8;
        int r = atomicAdd(&cur[b], 1);
        pairs[(size_t)b * SLACK + base[b] + r] = (unsigned)src[i] | ((unsigned)(d & 255) << 16);
    }
}
// K2: one block per bucket: hist 256 dsts -> scan -> beg/end/dinv; rank-scatter src into col
// (col region per bucket <=32KB, written by one block -> L2-local)
__global__ __launch_bounds__(256) void bbuild_k(const unsigned int* __restrict__ pairs,
    const int* __restrict__ bcur,
    int* __restrict__ beg, int* __restrict__ endp, float* __restrict__ dinv,
    int* __restrict__ col)
{
    __shared__ int h[256], cur[256], exc[256], sh[256];
    int b = blockIdx.x, t = threadIdx.x;
    int nb = bcur[b];
    size_t rb = (size_t)b * SLACK;
    int d0 = b << 8;
    int nd = NN - d0; if (nd > 256) nd = 256;
    h[t] = 0; cur[t] = 0;
    __syncthreads();
    for (int i = t; i < nb; i += 256) atomicAdd(&h[(pairs[rb + i] >> 16) & 255], 1);
    __syncthreads();
    int v = h[t];
    sh[t] = v; __syncthreads();
    for (int off = 1; off < 256; off <<= 1) {
        int u = (t >= off) ? sh[t - off] : 0;
        __syncthreads();
        sh[t] += u;
        __syncthreads();
    }
    int ex = sh[t] - v;
    exc[t] = ex;
    if (t < nd) {
        beg[d0 + t]  = (int)rb + ex;
        endp[d0 + t] = (int)rb + ex + v;
        dinv[d0 + t] = rsqrtf(1.0f + (float)v);
    }
    __syncthreads();
    for (int i = t; i < nb; i += 256) {
        unsigned p = pairs[rb + i];
        int dl = (p >> 16) & 255;
        int r = atomicAdd(&cur[dl], 1);
        col[rb + exc[dl] + r] = (int)(p & 0xFFFFu);
    }
}

// ---------------- bf16 helpers ----------------
__device__ inline void splitbf(float x, short& h, short& l) {
    unsigned int u = __float_as_uint(x);
    unsigned int r = u + 0x8000u;                 // round-to-nearest on hi
    short hh = (short)(r >> 16);
    float hf = __uint_as_float(((unsigned int)(unsigned short)hh) << 16);
    float lo = x - hf;
    unsigned int u2 = __float_as_uint(lo) + 0x8000u;
    h = hh;
    l = (short)(u2 >> 16);
}
__device__ inline unsigned short f2bf(float x) {   // RTNE
    unsigned int u = __float_as_uint(x);
    unsigned int r = u + 0x7FFFu + ((u >> 16) & 1u);
    return (unsigned short)(r >> 16);
}
__device__ inline float bf2f(unsigned short b) {
    return __uint_as_float(((unsigned int)b) << 16);
}

// ---------------- MFMA GEMM: outA[n,c] = epi( sum_k Xin[n,k] * W[c,k] ) --------
// W split to bf16 hi/lo in LDS.
// XBF=false: X fp32, 3-term (xh*wh + xh*wl + xl*wh)  [layer 1]
// XBF=true:  X already bf16, 2-term (x*wh + x*wl)    [layer 2, head]
// EPI==0: write (acc*dinv[row]) bf16 (gather source); EPI==1: relu(acc+bout) fp32
template<int CO, bool XBF, int EPI>
__global__ __launch_bounds__(256) void mgemm_k(
    const void* __restrict__ Xin, const float* __restrict__ W,
    const float* __restrict__ dinv,
    const float* __restrict__ bout, void* __restrict__ outAv)
{
    __shared__ short8 WhV[CO * 16];   // [c][granule], granule = 8 bf16 of k
    __shared__ short8 WlV[CO * 16];   // XOR-swizzled: slot = G ^ (c & 15)

    const int t = threadIdx.x;

    for (int i = t; i < CO * 16; i += 256) {
        int c = i >> 4, G = i & 15;
        const float* wp = W + c * KD + G * 8;
        float4 w0 = *(const float4*)wp;
        float4 w1 = *(const float4*)(wp + 4);
        float xs[8] = {w0.x, w0.y, w0.z, w0.w, w1.x, w1.y, w1.z, w1.w};
        short8 h, l;
#pragma unroll
        for (int j = 0; j < 8; ++j) { short hh, ll; splitbf(xs[j], hh, ll); h[j] = hh; l[j] = ll; }
        int Gs = G ^ (c & 15);
        WhV[c * 16 + Gs] = h;
        WlV[c * 16 + Gs] = l;
    }
    __syncthreads();

    const int wv = t >> 6, l = t & 63, q = l >> 4, lr = l & 15;
    const int row0 = blockIdx.x * 64 + wv * 16;
    constexpr int NCT = CO / 16;

    f32x4 acc[NCT];
#pragma unroll
    for (int ct = 0; ct < NCT; ++ct) acc[ct] = (f32x4){0.f, 0.f, 0.f, 0.f};

    int xrow = row0 + lr; if (xrow > NN - 1) xrow = NN - 1;   // clamp (stores guarded)

#pragma unroll
    for (int kk = 0; kk < 4; ++kk) {
        short8 ah, al;
        if (XBF) {
            ah = *(const short8*)((const unsigned short*)Xin + (size_t)xrow * KD + q * 8 + kk * 32);
        } else {
            const float* xbase = (const float*)Xin + (size_t)xrow * KD + q * 8 + kk * 32;
            float4 x0 = *(const float4*)xbase;
            float4 x1 = *(const float4*)(xbase + 4);
            float xs[8] = {x0.x, x0.y, x0.z, x0.w, x1.x, x1.y, x1.z, x1.w};
#pragma unroll
            for (int j = 0; j < 8; ++j) { short hh, ll; splitbf(xs[j], hh, ll); ah[j] = hh; al[j] = ll; }
        }

#pragma unroll
        for (int ct = 0; ct < NCT; ++ct) {
            int c = ct * 16 + lr;
            int Gs = (kk * 4 + q) ^ (c & 15);
            short8 bh = WhV[c * 16 + Gs];
            short8 bl = WlV[c * 16 + Gs];
            acc[ct] = __builtin_amdgcn_mfma_f32_16x16x32_bf16(ah, bh, acc[ct], 0, 0, 0);
            acc[ct] = __builtin_amdgcn_mfma_f32_16x16x32_bf16(ah, bl, acc[ct], 0, 0, 0);
            if (!XBF)
                acc[ct] = __builtin_amdgcn_mfma_f32_16x16x32_bf16(al, bh, acc[ct], 0, 0, 0);
        }
    }

    // ---- epilogue: D[row=(q*4+r)][col=lane&15] per C/D mapping
    float dv[4]; int rok[4];
#pragma unroll
    for (int r = 0; r < 4; ++r) {
        int row = row0 + q * 4 + r;
        rok[r] = (row < NN);
        dv[r] = (EPI == 0 && rok[r]) ? dinv[row] : 0.f;
    }
#pragma unroll
    for (int ct = 0; ct < NCT; ++ct) {
        int c = ct * 16 + lr;
        float bc = (EPI == 1) ? bout[c] : 0.f;
#pragma unroll
        for (int r = 0; r < 4; ++r) {
            int row = row0 + q * 4 + r;
            if (rok[r]) {
                float v = acc[ct][r];
                if (EPI == 0) {
                    ((unsigned short*)outAv)[(size_t)row * CO + c] = f2bf(v * dv[r]);
                } else {
                    ((float*)outAv)[(size_t)row * CO + c] = fmaxf(0.f, v + bc);
                }
            }
        }
    }
}

// ---------------- CSR gather + next-layer input transform -----------------
// outX[d,:] = relu( dinv[d]*(A[d,:] + sum_{s in adj(d)} A[s,:]) + bias ) as bf16
// A bf16 [N][128]. Direct col[j] loads, parity halves, 4-deep unroll (R9-proven).
__global__ __launch_bounds__(256) void gather_k(
    const unsigned short* __restrict__ Hs, unsigned short* __restrict__ outX,
    const int* __restrict__ begp, const int* __restrict__ endpp,
    const int* __restrict__ col,
    const float* __restrict__ dinv, const float* __restrict__ bias)
{
    int wave = threadIdx.x >> 6;
    int lane = threadIdx.x & 63;
    int h  = lane >> 5;          // neighbor parity handled by this half-wave
    int sl = lane & 31;          // channel chunk: channels [4*sl, 4*sl+3]
    int d = blockIdx.x * 4 + wave;
    if (d >= NN) return;
    int beg = begp[d], end = endpp[d];

    const unsigned short* hp = Hs + sl * 4;
    float4 bb = *(const float4*)(bias + sl * 4);

    float4 a0 = make_float4(0.f, 0.f, 0.f, 0.f);
    float4 a1 = make_float4(0.f, 0.f, 0.f, 0.f);
    float4 a2 = make_float4(0.f, 0.f, 0.f, 0.f);
    float4 a3 = make_float4(0.f, 0.f, 0.f, 0.f);

    if (h == 0) {                                   // self-loop term on even half
        us4 v = *(const us4*)(hp + (size_t)d * KD);
        a0.x = bf2f(v[0]); a0.y = bf2f(v[1]); a0.z = bf2f(v[2]); a0.w = bf2f(v[3]);
    }

    int j = beg + h;
    for (; j + 6 < end; j += 8) {                   // 4-deep, stride 2 per half
        int s0 = col[j],     s1 = col[j + 2];
        int s2 = col[j + 4], s3 = col[j + 6];
        us4 v0 = *(const us4*)(hp + (size_t)s0 * KD);
        us4 v1 = *(const us4*)(hp + (size_t)s1 * KD);
        us4 v2 = *(const us4*)(hp + (size_t)s2 * KD);
        us4 v3 = *(const us4*)(hp + (size_t)s3 * KD);
        a0.x += bf2f(v0[0]); a0.y += bf2f(v0[1]); a0.z += bf2f(v0[2]); a0.w += bf2f(v0[3]);
        a1.x += bf2f(v1[0]); a1.y += bf2f(v1[1]); a1.z += bf2f(v1[2]); a1.w += bf2f(v1[3]);
        a2.x += bf2f(v2[0]); a2.y += bf2f(v2[1]); a2.z += bf2f(v2[2]); a2.w += bf2f(v2[3]);
        a3.x += bf2f(v3[0]); a3.y += bf2f(v3[1]); a3.z += bf2f(v3[2]); a3.w += bf2f(v3[3]);
    }
    for (; j < end; j += 2) {                       // remainder (same parity)
        int s = col[j];
        us4 v = *(const us4*)(hp + (size_t)s * KD);
        a0.x += bf2f(v[0]); a0.y += bf2f(v[1]); a0.z += bf2f(v[2]); a0.w += bf2f(v[3]);
    }

    float4 tt;
    tt.x = (a0.x + a1.x) + (a2.x + a3.x);
    tt.y = (a0.y + a1.y) + (a2.y + a3.y);
    tt.z = (a0.z + a1.z) + (a2.z + a3.z);
    tt.w = (a0.w + a1.w) + (a2.w + a3.w);
    tt.x += __shfl_xor(tt.x, 32);                   // combine parities across halves
    tt.y += __shfl_xor(tt.y, 32);
    tt.z += __shfl_xor(tt.z, 32);
    tt.w += __shfl_xor(tt.w, 32);

    if (h == 0) {
        float dvv = dinv[d];
        us4 r;
        r[0] = f2bf(fmaxf(0.f, tt.x * dvv + bb.x));
        r[1] = f2bf(fmaxf(0.f, tt.y * dvv + bb.y));
        r[2] = f2bf(fmaxf(0.f, tt.z * dvv + bb.z));
        r[3] = f2bf(fmaxf(0.f, tt.w * dvv + bb.w));
        *(us4*)(outX + (size_t)d * KD + sl * 4) = r;
    }
}

extern "C" void kernel_launch(void* const* d_in, const int* in_sizes, int n_in,
                              void* d_out, int out_size, void* d_ws, size_t ws_size,
                              hipStream_t stream) {
    const float* x    = (const float*)d_in[0];
    const int*   ei   = (const int*)d_in[1];     // [2,E] int32
    const float* W1   = (const float*)d_in[2];
    const float* b1   = (const float*)d_in[3];
    const float* W2   = (const float*)d_in[4];
    const float* b2   = (const float*)d_in[5];
    const float* Wp   = (const float*)d_in[6];
    const float* bp   = (const float*)d_in[7];
    float* out = (float*)d_out;

    const int* esrc = ei;
    const int* edst = ei + NE;

    unsigned short* A  = (unsigned short*)d_ws;       // bf16 Hs       [N,128] 12.8 MB
    unsigned short* X2 = A + (size_t)NN * KD;         // bf16 next-X   [N,128] 12.8 MB
    float* dinv   = (float*)(X2 + (size_t)NN * KD);   // [N]
    int*   beg    = (int*)(dinv + NN);                // [N]
    int*   endp   = beg + NN;                         // [N]
    int*   col    = endp + NN;                        // [NBUK*SLACK] 6.4 MB
    unsigned int* pairs = (unsigned int*)(col + NBUK * SLACK); // [NBUK*SLACK] 6.4 MB
    int*   bcur   = (int*)(pairs + (size_t)NBUK * SLACK);      // [NBUK]

    const int NCH = (NE + CHUNK - 1) / CHUNK;         // 391

    // ---- CSR by dst (+ dinv) via direct-bucket counting sort ----
    zero196_k<<<1, 256, 0, stream>>>(bcur);
    bscat_k <<<NCH, 256, 0, stream>>>(esrc, edst, bcur, pairs, NE);
    bbuild_k<<<NBUK, 256, 0, stream>>>(pairs, bcur, beg, endp, dinv, col);

    const int GB = (NN + 63) / 64;      // 782 mfma-gemm blocks
    const int AB = (NN + 3) / 4;        // 12500 gather blocks (4 waves/block)

    // layer 1: Hs1 = (x@W1^T)*dinv -> A (bf16)
    mgemm_k<128, false, 0><<<GB, 256, 0, stream>>>(x, W1, dinv, nullptr, A);
    // gather + transform: X2 = relu(dinv*(A+sum) + b1)  (bf16)
    gather_k<<<AB, 256, 0, stream>>>(A, X2, beg, endp, col, dinv, b1);
    // layer 2: Hs2 = (X2@W2^T)*dinv -> A (bf16), 2-term MFMA
    mgemm_k<128, true, 0><<<GB, 256, 0, stream>>>(X2, W2, dinv, nullptr, A);
    // gather + transform: X2 = relu(dinv*(A+sum) + b2)  (bf16)
    gather_k<<<AB, 256, 0, stream>>>(A, X2, beg, endp, col, dinv, b2);
    // head: out = relu(X2@Wp^T + bp)  fp32
    mgemm_k<64, true, 1><<<GB, 256, 0, stream>>>(X2, Wp, dinv, bp, out);
}

// Round 13
// 163.858 us; speedup vs baseline: 17.6624x; 1.0131x over previous
//
#include <hip/hip_runtime.h>

#define NN 50000
#define NE 800000
#define KD 128    // inner dim (IN_C == HID_C == 128)
#define NBUK 196  // ceil(NN/256) buckets by dst>>8
#define CHUNK 2048
#define SLACK 8192  // fixed bucket region size (mean 4082, +64 sigma safe)

typedef __attribute__((ext_vector_type(8))) short short8;
typedef __attribute__((ext_vector_type(4))) float f32x4;
typedef __attribute__((ext_vector_type(4))) unsigned short us4;

// ---------------- bf16 helpers ----------------
__device__ inline void splitbf(float x, short& h, short& l) {
    unsigned int u = __float_as_uint(x);
    unsigned int r = u + 0x8000u;                 // round-to-nearest on hi
    short hh = (short)(r >> 16);
    float hf = __uint_as_float(((unsigned int)(unsigned short)hh) << 16);
    float lo = x - hf;
    unsigned int u2 = __float_as_uint(lo) + 0x8000u;
    h = hh;
    l = (short)(u2 >> 16);
}
__device__ inline unsigned short f2bf(float x) {   // RTNE
    unsigned int u = __float_as_uint(x);
    unsigned int r = u + 0x7FFFu + ((u >> 16) & 1u);
    return (unsigned short)(r >> 16);
}
__device__ inline float bf2f(unsigned short b) {
    return __uint_as_float(((unsigned int)b) << 16);
}

// ---------------- W pre-split: all three weights -> bf16 hi/lo (RTNE, once) -------
// layout: [W1: 16384][W2: 16384][Wp: 8192] row-major [c][k]
// block 0 also zeroes the bucket cursors (completes before bscat_k launches).
__global__ __launch_bounds__(256) void wsplit_k(
    const float* __restrict__ W1, const float* __restrict__ W2, const float* __restrict__ Wp,
    unsigned short* __restrict__ Wh, unsigned short* __restrict__ Wl,
    int* __restrict__ bcur)
{
    int t = threadIdx.x;
    if (blockIdx.x == 0 && t < NBUK) bcur[t] = 0;
    int i = blockIdx.x * 256 + t;                  // 0..40959
    float w;
    if (i < 16384) w = W1[i];
    else if (i < 32768) w = W2[i - 16384];
    else w = Wp[i - 32768];
    short h, l;
    splitbf(w, h, l);
    Wh[i] = (unsigned short)h;
    Wl[i] = (unsigned short)l;
}

// ---------------- CSR build: direct-bucket counting sort (no count/scan passes) ----
// K1: per-chunk LDS histogram -> claim per-bucket runs off global cursors ->
//     write packed (src:u16, dst&255:bits16-23) into fixed-stride bucket regions
__global__ __launch_bounds__(256) void bscat_k(const int* __restrict__ src, const int* __restrict__ dst,
    int* __restrict__ bcur, unsigned int* __restrict__ pairs, int e)
{
    __shared__ int h[NBUK], base[NBUK], cur[NBUK];
    int t = threadIdx.x;
    int e0 = blockIdx.x * CHUNK, e1 = min(e0 + CHUNK, e);
    for (int i = t; i < NBUK; i += 256) { h[i] = 0; cur[i] = 0; }
    __syncthreads();
    for (int i = e0 + t; i < e1; i += 256) atomicAdd(&h[dst[i] >> 8], 1);
    __syncthreads();
    for (int i = t; i < NBUK; i += 256) base[i] = h[i] ? atomicAdd(&bcur[i], h[i]) : 0;
    __syncthreads();
    for (int i = e0 + t; i < e1; i += 256) {
        int d = dst[i];
        int b = d >> 8;
        int r = atomicAdd(&cur[b], 1);
        pairs[(size_t)b * SLACK + base[b] + r] = (unsigned)src[i] | ((unsigned)(d & 255) << 16);
    }
}
// K2: one block per bucket: hist 256 dsts -> scan -> beg/end/dinv; rank-scatter src into col
__global__ __launch_bounds__(256) void bbuild_k(const unsigned int* __restrict__ pairs,
    const int* __restrict__ bcur,
    int* __restrict__ beg, int* __restrict__ endp, float* __restrict__ dinv,
    int* __restrict__ col)
{
    __shared__ int h[256], cur[256], exc[256], sh[256];
    int b = blockIdx.x, t = threadIdx.x;
    int nb = bcur[b];
    size_t rb = (size_t)b * SLACK;
    int d0 = b << 8;
    int nd = NN - d0; if (nd > 256) nd = 256;
    h[t] = 0; cur[t] = 0;
    __syncthreads();
    for (int i = t; i < nb; i += 256) atomicAdd(&h[(pairs[rb + i] >> 16) & 255], 1);
    __syncthreads();
    int v = h[t];
    sh[t] = v; __syncthreads();
    for (int off = 1; off < 256; off <<= 1) {
        int u = (t >= off) ? sh[t - off] : 0;
        __syncthreads();
        sh[t] += u;
        __syncthreads();
    }
    int ex = sh[t] - v;
    exc[t] = ex;
    if (t < nd) {
        beg[d0 + t]  = (int)rb + ex;
        endp[d0 + t] = (int)rb + ex + v;
        dinv[d0 + t] = rsqrtf(1.0f + (float)v);
    }
    __syncthreads();
    for (int i = t; i < nb; i += 256) {
        unsigned p = pairs[rb + i];
        int dl = (p >> 16) & 255;
        int r = atomicAdd(&cur[dl], 1);
        col[rb + exc[dl] + r] = (int)(p & 0xFFFFu);
    }
}

// ---------------- MFMA GEMM: outA[n,c] = epi( sum_k Xin[n,k] * W[c,k] ) --------
// W pre-split bf16 hi/lo in global; staged (pure copy) into XOR-swizzled LDS.
// XBF=false: X fp32, 3-term (xh*wh + xh*wl + xl*wh)  [layer 1]
// XBF=true:  X already bf16, 2-term (x*wh + x*wl)    [layer 2, head]
// EPI==0: write (acc*dinv[row]) bf16 (gather source); EPI==1: relu(acc+bout) fp32
template<int CO, bool XBF, int EPI>
__global__ __launch_bounds__(256) void mgemm_k(
    const void* __restrict__ Xin,
    const unsigned short* __restrict__ Wh, const unsigned short* __restrict__ Wl,
    const float* __restrict__ dinv,
    const float* __restrict__ bout, void* __restrict__ outAv)
{
    __shared__ short8 WhV[CO * 16];   // [c][granule], granule = 8 bf16 of k
    __shared__ short8 WlV[CO * 16];   // XOR-swizzled: slot = G ^ (c & 15)

    const int t = threadIdx.x;

    for (int i = t; i < CO * 16; i += 256) {
        int c = i >> 4, G = i & 15;
        short8 h = *(const short8*)(Wh + c * KD + G * 8);
        short8 l = *(const short8*)(Wl + c * KD + G * 8);
        int Gs = G ^ (c & 15);
        WhV[c * 16 + Gs] = h;
        WlV[c * 16 + Gs] = l;
    }
    __syncthreads();

    const int wv = t >> 6, l = t & 63, q = l >> 4, lr = l & 15;
    const int row0 = blockIdx.x * 64 + wv * 16;
    constexpr int NCT = CO / 16;

    f32x4 acc[NCT];
#pragma unroll
    for (int ct = 0; ct < NCT; ++ct) acc[ct] = (f32x4){0.f, 0.f, 0.f, 0.f};

    int xrow = row0 + lr; if (xrow > NN - 1) xrow = NN - 1;   // clamp (stores guarded)

#pragma unroll
    for (int kk = 0; kk < 4; ++kk) {
        short8 ah, al;
        if (XBF) {
            ah = *(const short8*)((const unsigned short*)Xin + (size_t)xrow * KD + q * 8 + kk * 32);
        } else {
            const float* xbase = (const float*)Xin + (size_t)xrow * KD + q * 8 + kk * 32;
            float4 x0 = *(const float4*)xbase;
            float4 x1 = *(const float4*)(xbase + 4);
            float xs[8] = {x0.x, x0.y, x0.z, x0.w, x1.x, x1.y, x1.z, x1.w};
#pragma unroll
            for (int j = 0; j < 8; ++j) { short hh, ll; splitbf(xs[j], hh, ll); ah[j] = hh; al[j] = ll; }
        }

#pragma unroll
        for (int ct = 0; ct < NCT; ++ct) {
            int c = ct * 16 + lr;
            int Gs = (kk * 4 + q) ^ (c & 15);
            short8 bh = WhV[c * 16 + Gs];
            short8 bl = WlV[c * 16 + Gs];
            acc[ct] = __builtin_amdgcn_mfma_f32_16x16x32_bf16(ah, bh, acc[ct], 0, 0, 0);
            acc[ct] = __builtin_amdgcn_mfma_f32_16x16x32_bf16(ah, bl, acc[ct], 0, 0, 0);
            if (!XBF)
                acc[ct] = __builtin_amdgcn_mfma_f32_16x16x32_bf16(al, bh, acc[ct], 0, 0, 0);
        }
    }

    // ---- epilogue: D[row=(q*4+r)][col=lane&15] per C/D mapping
    float dv[4]; int rok[4];
#pragma unroll
    for (int r = 0; r < 4; ++r) {
        int row = row0 + q * 4 + r;
        rok[r] = (row < NN);
        dv[r] = (EPI == 0 && rok[r]) ? dinv[row] : 0.f;
    }
#pragma unroll
    for (int ct = 0; ct < NCT; ++ct) {
        int c = ct * 16 + lr;
        float bc = (EPI == 1) ? bout[c] : 0.f;
#pragma unroll
        for (int r = 0; r < 4; ++r) {
            int row = row0 + q * 4 + r;
            if (rok[r]) {
                float v = acc[ct][r];
                if (EPI == 0) {
                    ((unsigned short*)outAv)[(size_t)row * CO + c] = f2bf(v * dv[r]);
                } else {
                    ((float*)outAv)[(size_t)row * CO + c] = fmaxf(0.f, v + bc);
                }
            }
        }
    }
}

// ---------------- CSR gather + next-layer input transform -----------------
// outX[d,:] = relu( dinv[d]*(A[d,:] + sum_{s in adj(d)} A[s,:]) + bias ) as bf16
// A bf16 [N][128]. Direct col[j] loads, parity halves, 4-deep unroll (R9-proven).
__global__ __launch_bounds__(256) void gather_k(
    const unsigned short* __restrict__ Hs, unsigned short* __restrict__ outX,
    const int* __restrict__ begp, const int* __restrict__ endpp,
    const int* __restrict__ col,
    const float* __restrict__ dinv, const float* __restrict__ bias)
{
    int wave = threadIdx.x >> 6;
    int lane = threadIdx.x & 63;
    int h  = lane >> 5;          // neighbor parity handled by this half-wave
    int sl = lane & 31;          // channel chunk: channels [4*sl, 4*sl+3]
    int d = blockIdx.x * 4 + wave;
    if (d >= NN) return;
    int beg = begp[d], end = endpp[d];

    const unsigned short* hp = Hs + sl * 4;
    float4 bb = *(const float4*)(bias + sl * 4);

    float4 a0 = make_float4(0.f, 0.f, 0.f, 0.f);
    float4 a1 = make_float4(0.f, 0.f, 0.f, 0.f);
    float4 a2 = make_float4(0.f, 0.f, 0.f, 0.f);
    float4 a3 = make_float4(0.f, 0.f, 0.f, 0.f);

    if (h == 0) {                                   // self-loop term on even half
        us4 v = *(const us4*)(hp + (size_t)d * KD);
        a0.x = bf2f(v[0]); a0.y = bf2f(v[1]); a0.z = bf2f(v[2]); a0.w = bf2f(v[3]);
    }

    int j = beg + h;
    for (; j + 6 < end; j += 8) {                   // 4-deep, stride 2 per half
        int s0 = col[j],     s1 = col[j + 2];
        int s2 = col[j + 4], s3 = col[j + 6];
        us4 v0 = *(const us4*)(hp + (size_t)s0 * KD);
        us4 v1 = *(const us4*)(hp + (size_t)s1 * KD);
        us4 v2 = *(const us4*)(hp + (size_t)s2 * KD);
        us4 v3 = *(const us4*)(hp + (size_t)s3 * KD);
        a0.x += bf2f(v0[0]); a0.y += bf2f(v0[1]); a0.z += bf2f(v0[2]); a0.w += bf2f(v0[3]);
        a1.x += bf2f(v1[0]); a1.y += bf2f(v1[1]); a1.z += bf2f(v1[2]); a1.w += bf2f(v1[3]);
        a2.x += bf2f(v2[0]); a2.y += bf2f(v2[1]); a2.z += bf2f(v2[2]); a2.w += bf2f(v2[3]);
        a3.x += bf2f(v3[0]); a3.y += bf2f(v3[1]); a3.z += bf2f(v3[2]); a3.w += bf2f(v3[3]);
    }
    for (; j < end; j += 2) {                       // remainder (same parity)
        int s = col[j];
        us4 v = *(const us4*)(hp + (size_t)s * KD);
        a0.x += bf2f(v[0]); a0.y += bf2f(v[1]); a0.z += bf2f(v[2]); a0.w += bf2f(v[3]);
    }

    float4 tt;
    tt.x = (a0.x + a1.x) + (a2.x + a3.x);
    tt.y = (a0.y + a1.y) + (a2.y + a3.y);
    tt.z = (a0.z + a1.z) + (a2.z + a3.z);
    tt.w = (a0.w + a1.w) + (a2.w + a3.w);
    tt.x += __shfl_xor(tt.x, 32);                   // combine parities across halves
    tt.y += __shfl_xor(tt.y, 32);
    tt.z += __shfl_xor(tt.z, 32);
    tt.w += __shfl_xor(tt.w, 32);

    if (h == 0) {
        float dvv = dinv[d];
        us4 r;
        r[0] = f2bf(fmaxf(0.f, tt.x * dvv + bb.x));
        r[1] = f2bf(fmaxf(0.f, tt.y * dvv + bb.y));
        r[2] = f2bf(fmaxf(0.f, tt.z * dvv + bb.z));
        r[3] = f2bf(fmaxf(0.f, tt.w * dvv + bb.w));
        *(us4*)(outX + (size_t)d * KD + sl * 4) = r;
    }
}

extern "C" void kernel_launch(void* const* d_in, const int* in_sizes, int n_in,
                              void* d_out, int out_size, void* d_ws, size_t ws_size,
                              hipStream_t stream) {
    const float* x    = (const float*)d_in[0];
    const int*   ei   = (const int*)d_in[1];     // [2,E] int32
    const float* W1   = (const float*)d_in[2];
    const float* b1   = (const float*)d_in[3];
    const float* W2   = (const float*)d_in[4];
    const float* b2   = (const float*)d_in[5];
    const float* Wp   = (const float*)d_in[6];
    const float* bp   = (const float*)d_in[7];
    float* out = (float*)d_out;

    const int* esrc = ei;
    const int* edst = ei + NE;

    unsigned short* A  = (unsigned short*)d_ws;       // bf16 Hs       [N,128] 12.8 MB
    unsigned short* X2 = A + (size_t)NN * KD;         // bf16 next-X   [N,128] 12.8 MB
    float* dinv   = (float*)(X2 + (size_t)NN * KD);   // [N]
    int*   beg    = (int*)(dinv + NN);                // [N]
    int*   endp   = beg + NN;                         // [N]
    int*   col    = endp + NN;                        // [NBUK*SLACK] 6.4 MB
    unsigned int* pairs = (unsigned int*)(col + NBUK * SLACK); // [NBUK*SLACK] 6.4 MB
    int*   bcur   = (int*)(pairs + (size_t)NBUK * SLACK);      // [NBUK]
    unsigned short* Wh = (unsigned short*)(bcur + NBUK);       // [40960]
    unsigned short* Wl = Wh + 40960;                           // [40960]

    const int NCH = (NE + CHUNK - 1) / CHUNK;         // 391

    // ---- W pre-split (+ cursor zero in block 0) ----
    wsplit_k<<<160, 256, 0, stream>>>(W1, W2, Wp, Wh, Wl, bcur);
    // ---- CSR by dst (+ dinv) via direct-bucket counting sort ----
    bscat_k <<<NCH, 256, 0, stream>>>(esrc, edst, bcur, pairs, NE);
    bbuild_k<<<NBUK, 256, 0, stream>>>(pairs, bcur, beg, endp, dinv, col);

    const int GB = (NN + 63) / 64;      // 782 mfma-gemm blocks
    const int AB = (NN + 3) / 4;        // 12500 gather blocks (4 waves/block)

    // layer 1: Hs1 = (x@W1^T)*dinv -> A (bf16)
    mgemm_k<128, false, 0><<<GB, 256, 0, stream>>>(x, Wh, Wl, dinv, nullptr, A);
    // gather + transform: X2 = relu(dinv*(A+sum) + b1)  (bf16)
    gather_k<<<AB, 256, 0, stream>>>(A, X2, beg, endp, col, dinv, b1);
    // layer 2: Hs2 = (X2@W2^T)*dinv -> A (bf16), 2-term MFMA
    mgemm_k<128, true, 0><<<GB, 256, 0, stream>>>(X2, Wh + 16384, Wl + 16384, dinv, nullptr, A);
    // gather + transform: X2 = relu(dinv*(A+sum) + b2)  (bf16)
    gather_k<<<AB, 256, 0, stream>>>(A, X2, beg, endp, col, dinv, b2);
    // head: out = relu(X2@Wp^T + bp)  fp32
    mgemm_k<64, true, 1><<<GB, 256, 0, stream>>>(X2, Wh + 32768, Wl + 32768, dinv, bp, out);
}